// Round 11
// baseline (221.463 us; speedup 1.0000x reference)
//
#include <hip/hip_runtime.h>
#include <math.h>

#define NN 20000          // nodes per graph
#define NE 320000         // edges (before self loops)
#define ETOT (NE + NN)    // edges + self loops
#define NH 4              // heads
#define CH 64             // channels per head
#define HC 256            // NH*CH
#define FIN 128           // layer-1 input features
#define NEG_SLOPE 0.2f
#define CAP 64            // edges per softmax chunk (multiple of 4)
#define EST 68            // ew stride in floats
#define AGG_TPB 128       // 2 waves/block: shorter deg-variance tail, finer packing

typedef unsigned short ushort_t;
typedef unsigned int uint_t;
typedef _Float16 half8 __attribute__((ext_vector_type(8)));
typedef float f32x4 __attribute__((ext_vector_type(4)));

__device__ __forceinline__ ushort_t f2h_bits(float f) {
    union { _Float16 h; ushort_t u; } c; c.h = (_Float16)f;
    return c.u;
}

// ---------------- CSR build ----------------

__global__ void k_zero_i32(int* __restrict__ p, int n) {
    int i = blockIdx.x * blockDim.x + threadIdx.x;
    if (i < n) p[i] = 0;
}

__global__ void k_hist(const int* __restrict__ ei, int* __restrict__ counts) {
    int e = blockIdx.x * blockDim.x + threadIdx.x;
    if (e >= ETOT) return;
    int d = (e < NE) ? ei[NE + e] : (e - NE);
    atomicAdd(&counts[d], 1);
}

__global__ void k_scan(const int* __restrict__ counts, int* __restrict__ rowptr,
                       int* __restrict__ cursor) {
    __shared__ int part[1024];
    int tid = threadIdx.x;
    const int n = NN;
    int chunk = (n + 1023) / 1024;
    int b = tid * chunk;
    int e = min(b + chunk, n);
    int s = 0;
    for (int i = b; i < e; ++i) s += counts[i];
    part[tid] = s;
    __syncthreads();
    for (int off = 1; off < 1024; off <<= 1) {
        int v = (tid >= off) ? part[tid - off] : 0;
        __syncthreads();
        part[tid] += v;
        __syncthreads();
    }
    int ex = (tid > 0) ? part[tid - 1] : 0;
    for (int i = b; i < e; ++i) { rowptr[i] = ex; cursor[i] = ex; ex += counts[i]; }
    if (tid == 1023) rowptr[n] = part[1023];
}

__global__ void k_scatter(const int* __restrict__ ei, int* __restrict__ cursor,
                          int* __restrict__ col) {
    int e = blockIdx.x * blockDim.x + threadIdx.x;
    if (e >= ETOT) return;
    int s, d;
    if (e < NE) { s = ei[e]; d = ei[NE + e]; }
    else        { s = e - NE; d = s; }
    int pos = atomicAdd(&cursor[d], 1);
    col[pos] = s;
}

// ---------------- fused setup: weight transposes + x convert ----------------

#define SN1 (FIN * HC)                      // Wt1
#define SN2 (SN1 + HC * HC)                 // Wt2
#define SN3 (SN2 + HC * CH)                 // Wtf
#define SN4 (SN3 + (2 * NN * FIN) / 4)      // x convert (vec4)

__global__ void k_setup(const float* __restrict__ x, const float* __restrict__ W1,
                        const float* __restrict__ W2, const float* __restrict__ Wf,
                        ushort_t* __restrict__ Xh, ushort_t* __restrict__ Wt1,
                        ushort_t* __restrict__ Wt2, ushort_t* __restrict__ Wtf) {
    int i = blockIdx.x * blockDim.x + threadIdx.x;
    if (i < SN1) {
        int n = i / FIN, k = i - n * FIN;
        Wt1[i] = f2h_bits(W1[(size_t)k * HC + n]);
    } else if (i < SN2) {
        int j = i - SN1;
        int n = j / HC, k = j - n * HC;
        Wt2[j] = f2h_bits(W2[(size_t)k * HC + n]);
    } else if (i < SN3) {
        int j = i - SN2;
        int n = j / HC, k = j - n * HC;
        Wtf[j] = f2h_bits(Wf[(size_t)k * CH + n]);
    } else if (i < SN4) {
        int j = (i - SN3) * 4;
        float4 v = *reinterpret_cast<const float4*>(&x[j]);
        ushort4 u;
        u.x = f2h_bits(v.x); u.y = f2h_bits(v.y); u.z = f2h_bits(v.z); u.w = f2h_bits(v.w);
        *reinterpret_cast<ushort4*>(&Xh[j]) = u;
    }
}

// ---------------- 128x128 f16 MFMA GEMM + fused attention scores ----------------

__global__ __launch_bounds__(256) void k_gemm128(const ushort_t* __restrict__ A,
                                                 const ushort_t* __restrict__ Bt,
                                                 ushort_t* __restrict__ Ch,
                                                 const float* __restrict__ a_src,
                                                 const float* __restrict__ a_dst,
                                                 float* __restrict__ ssrc,
                                                 float* __restrict__ sdst,
                                                 int M, int K, int NC) {
    __shared__ ushort_t As[128 * 40];   // pad: 80B stride -> 2-way (free)
    __shared__ ushort_t Bs[128 * 40];
    int tid = threadIdx.x;
    int wave = tid >> 6, lane = tid & 63;
    int wr = wave >> 1, wc = wave & 1;
    int row0 = blockIdx.x * 128, col0 = blockIdx.y * 128;

    f32x4 acc[4][4];
#pragma unroll
    for (int i = 0; i < 4; ++i)
#pragma unroll
        for (int j = 0; j < 4; ++j) acc[i][j] = (f32x4){0.f, 0.f, 0.f, 0.f};

    int srow = tid >> 2;
    int sk8 = (tid & 3) * 8;
    int l15 = lane & 15, lk = (lane >> 4) * 8;

    int ra0 = min(row0 + srow, M - 1);
    int ra1 = min(row0 + 64 + srow, M - 1);

    for (int k0 = 0; k0 < K; k0 += 32) {
        uint4 a0 = *reinterpret_cast<const uint4*>(&A[(size_t)ra0 * K + k0 + sk8]);
        uint4 a1 = *reinterpret_cast<const uint4*>(&A[(size_t)ra1 * K + k0 + sk8]);
        uint4 b0 = *reinterpret_cast<const uint4*>(&Bt[(size_t)(col0 + srow) * K + k0 + sk8]);
        uint4 b1 = *reinterpret_cast<const uint4*>(&Bt[(size_t)(col0 + 64 + srow) * K + k0 + sk8]);
        __syncthreads();
        *reinterpret_cast<uint4*>(&As[srow * 40 + sk8]) = a0;
        *reinterpret_cast<uint4*>(&As[(64 + srow) * 40 + sk8]) = a1;
        *reinterpret_cast<uint4*>(&Bs[srow * 40 + sk8]) = b0;
        *reinterpret_cast<uint4*>(&Bs[(64 + srow) * 40 + sk8]) = b1;
        __syncthreads();

        half8 af[4], bf_[4];
#pragma unroll
        for (int m = 0; m < 4; ++m)
            af[m] = *reinterpret_cast<const half8*>(&As[(wr * 64 + m * 16 + l15) * 40 + lk]);
#pragma unroll
        for (int nf = 0; nf < 4; ++nf)
            bf_[nf] = *reinterpret_cast<const half8*>(&Bs[(wc * 64 + nf * 16 + l15) * 40 + lk]);
#pragma unroll
        for (int m = 0; m < 4; ++m)
#pragma unroll
            for (int nf = 0; nf < 4; ++nf)
                acc[m][nf] = __builtin_amdgcn_mfma_f32_16x16x32_f16(af[m], bf_[nf], acc[m][nf], 0, 0, 0);
    }

    // C store (f16)
#pragma unroll
    for (int m = 0; m < 4; ++m)
#pragma unroll
        for (int nf = 0; nf < 4; ++nf) {
            int colc = col0 + wc * 64 + nf * 16 + l15;
#pragma unroll
            for (int j = 0; j < 4; ++j) {
                int row = row0 + wr * 64 + m * 16 + (lane >> 4) * 4 + j;
                if (row < M) Ch[(size_t)row * NC + colc] = f2h_bits(acc[m][nf][j]);
            }
        }

    // fused scores: this wave's 64 cols = one full head
    if (ssrc) {
        int head = (col0 >> 6) + wc;
        float as4[4], ad4[4];
#pragma unroll
        for (int nf = 0; nf < 4; ++nf) {
            as4[nf] = a_src[head * 64 + nf * 16 + l15];
            ad4[nf] = a_dst[head * 64 + nf * 16 + l15];
        }
#pragma unroll
        for (int m = 0; m < 4; ++m)
#pragma unroll
            for (int j = 0; j < 4; ++j) {
                float ps = acc[m][0][j] * as4[0] + acc[m][1][j] * as4[1]
                         + acc[m][2][j] * as4[2] + acc[m][3][j] * as4[3];
                float pd = acc[m][0][j] * ad4[0] + acc[m][1][j] * ad4[1]
                         + acc[m][2][j] * ad4[2] + acc[m][3][j] * ad4[3];
#pragma unroll
                for (int off = 1; off < 16; off <<= 1) {
                    ps += __shfl_xor(ps, off);
                    pd += __shfl_xor(pd, off);
                }
                int row = row0 + wr * 64 + m * 16 + (lane >> 4) * 4 + j;
                if (l15 == 0 && row < M) {
                    ssrc[(size_t)row * NH + head] = ps;
                    sdst[(size_t)row * NH + head] = pd;
                }
            }
    }
}

// ---------------- 64x64 f16 MFMA GEMM (final projection, f32 out + bias) ----------------

__global__ __launch_bounds__(256) void k_gemm_mfma(const ushort_t* __restrict__ A,
                                                   const ushort_t* __restrict__ Bt,
                                                   float* __restrict__ Cf,
                                                   const float* __restrict__ bias,
                                                   int M, int K, int NC) {
    __shared__ ushort_t As[64][40];
    __shared__ ushort_t Bs[64][40];
    int tid = threadIdx.x;
    int wave = tid >> 6, lane = tid & 63;
    int wr = wave >> 1, wc = wave & 1;
    int row0 = blockIdx.x * 64, col0 = blockIdx.y * 64;

    f32x4 acc[2][2];
#pragma unroll
    for (int i = 0; i < 2; ++i)
#pragma unroll
        for (int j = 0; j < 2; ++j) acc[i][j] = (f32x4){0.f, 0.f, 0.f, 0.f};

    int sr = tid >> 2;
    int sk = (tid & 3) * 8;
    int l15 = lane & 15, lk = (lane >> 4) * 8;

    for (int k0 = 0; k0 < K; k0 += 32) {
        uint4 av = make_uint4(0, 0, 0, 0);
        int rowg = row0 + sr;
        if (rowg < M) av = *reinterpret_cast<const uint4*>(&A[(size_t)rowg * K + k0 + sk]);
        uint4 bv = *reinterpret_cast<const uint4*>(&Bt[(size_t)(col0 + sr) * K + k0 + sk]);
        __syncthreads();
        *reinterpret_cast<uint4*>(&As[sr][sk]) = av;
        *reinterpret_cast<uint4*>(&Bs[sr][sk]) = bv;
        __syncthreads();

        half8 a0 = *reinterpret_cast<const half8*>(&As[wr * 32 + l15][lk]);
        half8 a1 = *reinterpret_cast<const half8*>(&As[wr * 32 + 16 + l15][lk]);
        half8 b0 = *reinterpret_cast<const half8*>(&Bs[wc * 32 + l15][lk]);
        half8 b1 = *reinterpret_cast<const half8*>(&Bs[wc * 32 + 16 + l15][lk]);
        acc[0][0] = __builtin_amdgcn_mfma_f32_16x16x32_f16(a0, b0, acc[0][0], 0, 0, 0);
        acc[0][1] = __builtin_amdgcn_mfma_f32_16x16x32_f16(a0, b1, acc[0][1], 0, 0, 0);
        acc[1][0] = __builtin_amdgcn_mfma_f32_16x16x32_f16(a1, b0, acc[1][0], 0, 0, 0);
        acc[1][1] = __builtin_amdgcn_mfma_f32_16x16x32_f16(a1, b1, acc[1][1], 0, 0, 0);
    }

#pragma unroll
    for (int fr = 0; fr < 2; ++fr)
#pragma unroll
        for (int fc = 0; fc < 2; ++fc) {
            int colc = col0 + wc * 32 + fc * 16 + l15;
#pragma unroll
            for (int j = 0; j < 4; ++j) {
                int row = row0 + wr * 32 + fr * 16 + (lane >> 4) * 4 + j;
                if (row < M) Cf[(size_t)row * NC + colc] = acc[fr][fc][j] + bias[colc];
            }
        }
}

// ---------------- edge softmax + aggregation: one wave per (node, batch) ----------------
// Batch-sequential wave mapping; 2 waves/block (retire granularity = max of 2 degs,
// not 4); chunks padded to 4 (not 8) -> ~8% dead gather work instead of ~29%.
// No-max softmax (|e| <~ 20, exp safe in fp32). Plain __launch_bounds__ — forcing
// min-waves caused VGPR-32 spills in round 9 (WRITE_SIZE 20->118 MB).

__global__ __launch_bounds__(AGG_TPB) void k_agg(const ushort_t* __restrict__ hb,  // [2*NN][HC] f16
                                                 const float* __restrict__ ssrc,   // [2*NN][NH]
                                                 const float* __restrict__ sdst,
                                                 const int* __restrict__ rowptr,
                                                 const int* __restrict__ col,
                                                 const float* __restrict__ bias,
                                                 ushort_t* __restrict__ outh,      // [2*NN][HC] f16
                                                 int do_elu) {
    __shared__ int cols_lds[AGG_TPB / 64][CAP];
    __shared__ float e_lds[AGG_TPB / 64][4 * EST];
    int wave = threadIdx.x >> 6, lane = threadIdx.x & 63;
    int gw = blockIdx.x * (AGG_TPB / 64) + wave;   // global wave id in [0, 2*NN)
    int b = (gw >= NN) ? 1 : 0;
    int n = gw - b * NN;
    int* colw = cols_lds[wave];
    float* ew = e_lds[wave];
    int start = rowptr[n];
    int deg = rowptr[n + 1] - start;
    int es = lane >> 5;          // edge slot
    int cg = lane & 31;          // channel group: ch [8cg, 8cg+8)
    int hd = cg >> 3;            // head of this lane's channels

    const ushort_t* hbase = hb + (size_t)b * NN * HC;
    const float* ssrcb = ssrc + (size_t)b * NN * NH;

    float sd[4];
    {
        float4 s0 = *reinterpret_cast<const float4*>(&sdst[((size_t)b * NN + n) * NH]);
        sd[0] = s0.x; sd[1] = s0.y; sd[2] = s0.z; sd[3] = s0.w;
    }

    float pd[4], acc[8];
#pragma unroll
    for (int c = 0; c < 4; ++c) pd[c] = 0.f;
#pragma unroll
    for (int j = 0; j < 8; ++j) acc[j] = 0.f;

    const int cg8 = cg * 8;

    for (int c0 = 0; c0 < deg; c0 += CAP) {
        int cnt = min(CAP, deg - c0);
        int cnt4 = (cnt + 3) & ~3;

        // phase A: w = exp(leaky(e)) -> LDS, denominator partials in regs
        for (int i = lane; i < cnt4; i += 64) {
            if (i < cnt) {
                int s = col[start + c0 + i];
                colw[i] = s * HC;
                float4 p = *reinterpret_cast<const float4*>(&ssrcb[(size_t)s * NH]);
                float e[4];
                e[0] = p.x + sd[0]; e[1] = p.y + sd[1]; e[2] = p.z + sd[2]; e[3] = p.w + sd[3];
#pragma unroll
                for (int c = 0; c < 4; ++c) {
                    e[c] = fmaxf(e[c], NEG_SLOPE * e[c]);
                    float w = __expf(e[c]);
                    ew[c * EST + i] = w;
                    pd[c] += w;
                }
            } else {
                colw[i] = 0;
#pragma unroll
                for (int c = 0; c < 4; ++c) ew[c * EST + i] = 0.f;
            }
        }

        // phase C: edge-parallel gather, 4 edges/iter, 2x16B loads in flight per lane
        for (int i = 0; i < cnt4; i += 4) {
            int i0 = i + es, i1 = i + 2 + es;
            int o0 = colw[i0], o1 = colw[i1];
            float w0 = ew[hd * EST + i0], w1 = ew[hd * EST + i1];
            half8 v0 = *reinterpret_cast<const half8*>(hbase + o0 + cg8);
            half8 v1 = *reinterpret_cast<const half8*>(hbase + o1 + cg8);
#pragma unroll
            for (int j = 0; j < 8; ++j) acc[j] = fmaf((float)v0[j], w0, acc[j]);
#pragma unroll
            for (int j = 0; j < 8; ++j) acc[j] = fmaf((float)v1[j], w1, acc[j]);
        }
    }

    // denominator reduce (off the memory critical path)
#pragma unroll
    for (int off = 32; off > 0; off >>= 1)
#pragma unroll
        for (int c = 0; c < 4; ++c) pd[c] += __shfl_xor(pd[c], off);

    // reduce acc across edge slots
#pragma unroll
    for (int j = 0; j < 8; ++j) acc[j] += __shfl_xor(acc[j], 32);

    if (es == 0) {
        float inv = 1.0f / pd[hd];
        float4 b0 = *reinterpret_cast<const float4*>(&bias[cg8]);
        float4 b1 = *reinterpret_cast<const float4*>(&bias[cg8 + 4]);
        float bv[8] = {b0.x, b0.y, b0.z, b0.w, b1.x, b1.y, b1.z, b1.w};
        ushort_t o[8];
#pragma unroll
        for (int j = 0; j < 8; ++j) {
            float r = acc[j] * inv + bv[j];
            if (do_elu && r < 0.f) r = expm1f(r);
            o[j] = f2h_bits(r);
        }
        *reinterpret_cast<uint4*>(&outh[((size_t)b * NN + n) * HC + cg8]) =
            *reinterpret_cast<uint4*>(&o[0]);
    }
}

// ---------------- launch ----------------

extern "C" void kernel_launch(void* const* d_in, const int* in_sizes, int n_in,
                              void* d_out, int out_size, void* d_ws, size_t ws_size,
                              hipStream_t stream) {
    const float* x      = (const float*)d_in[0];   // [2, NN, FIN]
    const int*   ei     = (const int*)d_in[1];     // [2, NE]
    const float* W1     = (const float*)d_in[2];   // [FIN, HC]
    const float* a_src1 = (const float*)d_in[3];
    const float* a_dst1 = (const float*)d_in[4];
    const float* b1     = (const float*)d_in[5];
    const float* W2     = (const float*)d_in[6];   // [HC, HC]
    const float* a_src2 = (const float*)d_in[7];
    const float* a_dst2 = (const float*)d_in[8];
    const float* b2     = (const float*)d_in[9];
    const float* Wf     = (const float*)d_in[10];  // [HC, CH]
    const float* bf     = (const float*)d_in[11];
    float* out = (float*)d_out;                    // [2, NN, CH]

    const int M2 = 2 * NN;
    float* ws = (float*)d_ws;
    float* Ssrc = ws;                              // M2*NH
    float* Sdst = Ssrc + (size_t)M2 * NH;          // M2*NH
    ushort_t* Hb16 = (ushort_t*)(Sdst + (size_t)M2 * NH);  // M2*HC f16 (gemm out)
    ushort_t* Ob16 = Hb16 + (size_t)M2 * HC;       // M2*HC f16 (agg out)
    ushort_t* Xb16 = Ob16 + (size_t)M2 * HC;       // M2*FIN f16
    ushort_t* Wt1  = Xb16 + (size_t)M2 * FIN;      // HC*FIN
    ushort_t* Wt2  = Wt1 + (size_t)HC * FIN;       // HC*HC
    ushort_t* Wtf  = Wt2 + (size_t)HC * HC;        // CH*HC
    int* counts = (int*)(Wtf + (size_t)CH * HC);
    int* rowptr = counts + NN;
    int* cursor = rowptr + (NN + 1);
    int* colidx = cursor + NN;                     // ETOT

    // ---- CSR build ----
    k_zero_i32<<<(NN + 255) / 256, 256, 0, stream>>>(counts, NN);
    k_hist<<<(ETOT + 255) / 256, 256, 0, stream>>>(ei, counts);
    k_scan<<<1, 1024, 0, stream>>>(counts, rowptr, cursor);
    k_scatter<<<(ETOT + 255) / 256, 256, 0, stream>>>(ei, cursor, colidx);

    // ---- fused setup: weight transposes + x convert ----
    k_setup<<<(SN4 + 255) / 256, 256, 0, stream>>>(x, W1, W2, Wf, Xb16, Wt1, Wt2, Wtf);

    const int gM128 = (M2 + 127) / 128;        // 313
    const int gAgg = M2 / (AGG_TPB / 64);      // 20000 blocks x 2 waves
    // layer 1 (scores fused into GEMM epilogue)
    k_gemm128<<<dim3(gM128, HC / 128), 256, 0, stream>>>(Xb16, Wt1, Hb16, a_src1, a_dst1,
                                                         Ssrc, Sdst, M2, FIN, HC);
    k_agg<<<gAgg, AGG_TPB, 0, stream>>>(Hb16, Ssrc, Sdst, rowptr, colidx, b1, Ob16, 1);
    // layer 2
    k_gemm128<<<dim3(gM128, HC / 128), 256, 0, stream>>>(Ob16, Wt2, Hb16, a_src2, a_dst2,
                                                         Ssrc, Sdst, M2, HC, HC);
    k_agg<<<gAgg, AGG_TPB, 0, stream>>>(Hb16, Ssrc, Sdst, rowptr, colidx, b2, Ob16, 0);
    // final projection (64-wide): f32 out + bias
    k_gemm_mfma<<<dim3((M2 + 63) / 64, CH / 64), 256, 0, stream>>>(Ob16, Wtf, out, bf, M2, HC, CH);
}

// Round 12
// 211.935 us; speedup vs baseline: 1.0450x; 1.0450x over previous
//
#include <hip/hip_runtime.h>
#include <math.h>

#define NN 20000          // nodes per graph
#define NE 320000         // edges (before self loops)
#define ETOT (NE + NN)    // edges + self loops
#define NH 4              // heads
#define CH 64             // channels per head
#define HC 256            // NH*CH
#define FIN 128           // layer-1 input features
#define NEG_SLOPE 0.2f
#define CAP 64            // edges per softmax chunk (multiple of 4)
#define EST 68            // ew stride in floats
#define SCB 79            // scan blocks: 79*256 >= NN
#define AGG_BLOCKS 2048   // persistent k_agg grid (x4 waves = 8192 slots)
#define AGG_SLOTS (AGG_BLOCKS * 4)

typedef unsigned short ushort_t;
typedef unsigned int uint_t;
typedef _Float16 half8 __attribute__((ext_vector_type(8)));
typedef float f32x4 __attribute__((ext_vector_type(4)));

__device__ __forceinline__ ushort_t f2h_bits(float f) {
    union { _Float16 h; ushort_t u; } c; c.h = (_Float16)f;
    return c.u;
}

// ---------------- CSR build ----------------

__global__ void k_zero_i32(int* __restrict__ p, int n) {
    int i = blockIdx.x * blockDim.x + threadIdx.x;
    if (i < n) p[i] = 0;
}

__global__ void k_hist(const int* __restrict__ ei, int* __restrict__ counts) {
    int e = blockIdx.x * blockDim.x + threadIdx.x;
    if (e >= ETOT) return;
    int d = (e < NE) ? ei[NE + e] : (e - NE);
    atomicAdd(&counts[d], 1);
}

// parallel scan: per-block reduce -> top scan -> per-block local scan + apply
__global__ void k_scan_part(const int* __restrict__ counts, int* __restrict__ bsum) {
    __shared__ int red[256];
    int t = threadIdx.x;
    int i = blockIdx.x * 256 + t;
    red[t] = (i < NN) ? counts[i] : 0;
    __syncthreads();
#pragma unroll
    for (int off = 128; off > 0; off >>= 1) {
        if (t < off) red[t] += red[t + off];
        __syncthreads();
    }
    if (t == 0) bsum[blockIdx.x] = red[0];
}

__global__ void k_scan_top(const int* __restrict__ bsum, int* __restrict__ bpre) {
    __shared__ int s[128];
    int t = threadIdx.x;
    int own = (t < SCB) ? bsum[t] : 0;
    s[t] = own;
    __syncthreads();
#pragma unroll
    for (int off = 1; off < 128; off <<= 1) {
        int v = (t >= off) ? s[t - off] : 0;
        __syncthreads();
        s[t] += v;
        __syncthreads();
    }
    if (t < SCB) bpre[t] = s[t] - own;   // exclusive block prefix
}

__global__ void k_scan_apply(const int* __restrict__ counts, const int* __restrict__ bpre,
                             int* __restrict__ rowptr, int* __restrict__ cursor) {
    __shared__ int s[256];
    int t = threadIdx.x;
    int i = blockIdx.x * 256 + t;
    int c = (i < NN) ? counts[i] : 0;
    s[t] = c;
    __syncthreads();
#pragma unroll
    for (int off = 1; off < 256; off <<= 1) {
        int v = (t >= off) ? s[t - off] : 0;
        __syncthreads();
        s[t] += v;
        __syncthreads();
    }
    int ex = s[t] - c + bpre[blockIdx.x];
    if (i < NN) { rowptr[i] = ex; cursor[i] = ex; }
    if (i == NN - 1) rowptr[NN] = ex + c;
}

__global__ void k_scatter(const int* __restrict__ ei, int* __restrict__ cursor,
                          int* __restrict__ col) {
    int e = blockIdx.x * blockDim.x + threadIdx.x;
    if (e >= ETOT) return;
    int s, d;
    if (e < NE) { s = ei[e]; d = ei[NE + e]; }
    else        { s = e - NE; d = s; }
    int pos = atomicAdd(&cursor[d], 1);
    col[pos] = s;
}

// ---------------- fused setup: weight transposes + x convert ----------------

#define SN1 (FIN * HC)                      // Wt1
#define SN2 (SN1 + HC * HC)                 // Wt2
#define SN3 (SN2 + HC * CH)                 // Wtf
#define SN4 (SN3 + (2 * NN * FIN) / 4)      // x convert (vec4)

__global__ void k_setup(const float* __restrict__ x, const float* __restrict__ W1,
                        const float* __restrict__ W2, const float* __restrict__ Wf,
                        ushort_t* __restrict__ Xh, ushort_t* __restrict__ Wt1,
                        ushort_t* __restrict__ Wt2, ushort_t* __restrict__ Wtf) {
    int i = blockIdx.x * blockDim.x + threadIdx.x;
    if (i < SN1) {
        int n = i / FIN, k = i - n * FIN;
        Wt1[i] = f2h_bits(W1[(size_t)k * HC + n]);
    } else if (i < SN2) {
        int j = i - SN1;
        int n = j / HC, k = j - n * HC;
        Wt2[j] = f2h_bits(W2[(size_t)k * HC + n]);
    } else if (i < SN3) {
        int j = i - SN2;
        int n = j / HC, k = j - n * HC;
        Wtf[j] = f2h_bits(Wf[(size_t)k * CH + n]);
    } else if (i < SN4) {
        int j = (i - SN3) * 4;
        float4 v = *reinterpret_cast<const float4*>(&x[j]);
        ushort4 u;
        u.x = f2h_bits(v.x); u.y = f2h_bits(v.y); u.z = f2h_bits(v.z); u.w = f2h_bits(v.w);
        *reinterpret_cast<ushort4*>(&Xh[j]) = u;
    }
}

// ---------------- 128x128 f16 MFMA GEMM + fused attention scores ----------------

__global__ __launch_bounds__(256) void k_gemm128(const ushort_t* __restrict__ A,
                                                 const ushort_t* __restrict__ Bt,
                                                 ushort_t* __restrict__ Ch,
                                                 const float* __restrict__ a_src,
                                                 const float* __restrict__ a_dst,
                                                 float* __restrict__ ssrc,
                                                 float* __restrict__ sdst,
                                                 int M, int K, int NC) {
    __shared__ ushort_t As[128 * 40];   // pad: 80B stride -> 2-way (free)
    __shared__ ushort_t Bs[128 * 40];
    int tid = threadIdx.x;
    int wave = tid >> 6, lane = tid & 63;
    int wr = wave >> 1, wc = wave & 1;
    int row0 = blockIdx.x * 128, col0 = blockIdx.y * 128;

    f32x4 acc[4][4];
#pragma unroll
    for (int i = 0; i < 4; ++i)
#pragma unroll
        for (int j = 0; j < 4; ++j) acc[i][j] = (f32x4){0.f, 0.f, 0.f, 0.f};

    int srow = tid >> 2;
    int sk8 = (tid & 3) * 8;
    int l15 = lane & 15, lk = (lane >> 4) * 8;

    int ra0 = min(row0 + srow, M - 1);
    int ra1 = min(row0 + 64 + srow, M - 1);

    for (int k0 = 0; k0 < K; k0 += 32) {
        uint4 a0 = *reinterpret_cast<const uint4*>(&A[(size_t)ra0 * K + k0 + sk8]);
        uint4 a1 = *reinterpret_cast<const uint4*>(&A[(size_t)ra1 * K + k0 + sk8]);
        uint4 b0 = *reinterpret_cast<const uint4*>(&Bt[(size_t)(col0 + srow) * K + k0 + sk8]);
        uint4 b1 = *reinterpret_cast<const uint4*>(&Bt[(size_t)(col0 + 64 + srow) * K + k0 + sk8]);
        __syncthreads();
        *reinterpret_cast<uint4*>(&As[srow * 40 + sk8]) = a0;
        *reinterpret_cast<uint4*>(&As[(64 + srow) * 40 + sk8]) = a1;
        *reinterpret_cast<uint4*>(&Bs[srow * 40 + sk8]) = b0;
        *reinterpret_cast<uint4*>(&Bs[(64 + srow) * 40 + sk8]) = b1;
        __syncthreads();

        half8 af[4], bf_[4];
#pragma unroll
        for (int m = 0; m < 4; ++m)
            af[m] = *reinterpret_cast<const half8*>(&As[(wr * 64 + m * 16 + l15) * 40 + lk]);
#pragma unroll
        for (int nf = 0; nf < 4; ++nf)
            bf_[nf] = *reinterpret_cast<const half8*>(&Bs[(wc * 64 + nf * 16 + l15) * 40 + lk]);
#pragma unroll
        for (int m = 0; m < 4; ++m)
#pragma unroll
            for (int nf = 0; nf < 4; ++nf)
                acc[m][nf] = __builtin_amdgcn_mfma_f32_16x16x32_f16(af[m], bf_[nf], acc[m][nf], 0, 0, 0);
    }

    // C store (f16)
#pragma unroll
    for (int m = 0; m < 4; ++m)
#pragma unroll
        for (int nf = 0; nf < 4; ++nf) {
            int colc = col0 + wc * 64 + nf * 16 + l15;
#pragma unroll
            for (int j = 0; j < 4; ++j) {
                int row = row0 + wr * 64 + m * 16 + (lane >> 4) * 4 + j;
                if (row < M) Ch[(size_t)row * NC + colc] = f2h_bits(acc[m][nf][j]);
            }
        }

    // fused scores: this wave's 64 cols = one full head
    if (ssrc) {
        int head = (col0 >> 6) + wc;
        float as4[4], ad4[4];
#pragma unroll
        for (int nf = 0; nf < 4; ++nf) {
            as4[nf] = a_src[head * 64 + nf * 16 + l15];
            ad4[nf] = a_dst[head * 64 + nf * 16 + l15];
        }
#pragma unroll
        for (int m = 0; m < 4; ++m)
#pragma unroll
            for (int j = 0; j < 4; ++j) {
                float ps = acc[m][0][j] * as4[0] + acc[m][1][j] * as4[1]
                         + acc[m][2][j] * as4[2] + acc[m][3][j] * as4[3];
                float pd = acc[m][0][j] * ad4[0] + acc[m][1][j] * ad4[1]
                         + acc[m][2][j] * ad4[2] + acc[m][3][j] * ad4[3];
#pragma unroll
                for (int off = 1; off < 16; off <<= 1) {
                    ps += __shfl_xor(ps, off);
                    pd += __shfl_xor(pd, off);
                }
                int row = row0 + wr * 64 + m * 16 + (lane >> 4) * 4 + j;
                if (l15 == 0 && row < M) {
                    ssrc[(size_t)row * NH + head] = ps;
                    sdst[(size_t)row * NH + head] = pd;
                }
            }
    }
}

// ---------------- 64x64 f16 MFMA GEMM (final projection, f32 out + bias) ----------------

__global__ __launch_bounds__(256) void k_gemm_mfma(const ushort_t* __restrict__ A,
                                                   const ushort_t* __restrict__ Bt,
                                                   float* __restrict__ Cf,
                                                   const float* __restrict__ bias,
                                                   int M, int K, int NC) {
    __shared__ ushort_t As[64][40];
    __shared__ ushort_t Bs[64][40];
    int tid = threadIdx.x;
    int wave = tid >> 6, lane = tid & 63;
    int wr = wave >> 1, wc = wave & 1;
    int row0 = blockIdx.x * 64, col0 = blockIdx.y * 64;

    f32x4 acc[2][2];
#pragma unroll
    for (int i = 0; i < 2; ++i)
#pragma unroll
        for (int j = 0; j < 2; ++j) acc[i][j] = (f32x4){0.f, 0.f, 0.f, 0.f};

    int sr = tid >> 2;
    int sk = (tid & 3) * 8;
    int l15 = lane & 15, lk = (lane >> 4) * 8;

    for (int k0 = 0; k0 < K; k0 += 32) {
        uint4 av = make_uint4(0, 0, 0, 0);
        int rowg = row0 + sr;
        if (rowg < M) av = *reinterpret_cast<const uint4*>(&A[(size_t)rowg * K + k0 + sk]);
        uint4 bv = *reinterpret_cast<const uint4*>(&Bt[(size_t)(col0 + sr) * K + k0 + sk]);
        __syncthreads();
        *reinterpret_cast<uint4*>(&As[sr][sk]) = av;
        *reinterpret_cast<uint4*>(&Bs[sr][sk]) = bv;
        __syncthreads();

        half8 a0 = *reinterpret_cast<const half8*>(&As[wr * 32 + l15][lk]);
        half8 a1 = *reinterpret_cast<const half8*>(&As[wr * 32 + 16 + l15][lk]);
        half8 b0 = *reinterpret_cast<const half8*>(&Bs[wc * 32 + l15][lk]);
        half8 b1 = *reinterpret_cast<const half8*>(&Bs[wc * 32 + 16 + l15][lk]);
        acc[0][0] = __builtin_amdgcn_mfma_f32_16x16x32_f16(a0, b0, acc[0][0], 0, 0, 0);
        acc[0][1] = __builtin_amdgcn_mfma_f32_16x16x32_f16(a0, b1, acc[0][1], 0, 0, 0);
        acc[1][0] = __builtin_amdgcn_mfma_f32_16x16x32_f16(a1, b0, acc[1][0], 0, 0, 0);
        acc[1][1] = __builtin_amdgcn_mfma_f32_16x16x32_f16(a1, b1, acc[1][1], 0, 0, 0);
    }

#pragma unroll
    for (int fr = 0; fr < 2; ++fr)
#pragma unroll
        for (int fc = 0; fc < 2; ++fc) {
            int colc = col0 + wc * 32 + fc * 16 + l15;
#pragma unroll
            for (int j = 0; j < 4; ++j) {
                int row = row0 + wr * 32 + fr * 16 + (lane >> 4) * 4 + j;
                if (row < M) Cf[(size_t)row * NC + colc] = acc[fr][fc][j] + bias[colc];
            }
        }
}

// ---------------- edge softmax + aggregation: persistent grid-stride ----------------
// 2048 blocks x 4 waves = 8192 wave slots; wave processes gw = pass*8192 + slot.
// Pass-ordered sweep keeps in-flight nodes contiguous (batch-sequential in time,
// round-8 L2 win) while cutting dispatch ramp 10000 -> 2048 blocks.
// No-max softmax (|e| <~ 20, exp safe in fp32). Plain __launch_bounds__ — forcing
// min-waves caused VGPR-32 spills in round 9 (WRITE_SIZE 20->118 MB).

__global__ __launch_bounds__(256) void k_agg(const ushort_t* __restrict__ hb,  // [2*NN][HC] f16
                                             const float* __restrict__ ssrc,   // [2*NN][NH]
                                             const float* __restrict__ sdst,
                                             const int* __restrict__ rowptr,
                                             const int* __restrict__ col,
                                             const float* __restrict__ bias,
                                             ushort_t* __restrict__ outh,      // [2*NN][HC] f16
                                             int do_elu) {
    __shared__ int cols_lds[4][CAP];
    __shared__ float e_lds[4][4 * EST];
    int wave = threadIdx.x >> 6, lane = threadIdx.x & 63;
    int slot = blockIdx.x * 4 + wave;          // 0..AGG_SLOTS-1
    int* colw = cols_lds[wave];
    float* ew = e_lds[wave];
    int es = lane >> 5;          // edge slot
    int cg = lane & 31;          // channel group: ch [8cg, 8cg+8)
    int hd = cg >> 3;            // head of this lane's channels
    const int cg8 = cg * 8;

    for (int gw = slot; gw < 2 * NN; gw += AGG_SLOTS) {
        int b = (gw >= NN) ? 1 : 0;
        int n = gw - b * NN;
        int start = rowptr[n];
        int deg = rowptr[n + 1] - start;

        const ushort_t* hbase = hb + (size_t)b * NN * HC;
        const float* ssrcb = ssrc + (size_t)b * NN * NH;

        float sd[4];
        {
            float4 s0 = *reinterpret_cast<const float4*>(&sdst[((size_t)b * NN + n) * NH]);
            sd[0] = s0.x; sd[1] = s0.y; sd[2] = s0.z; sd[3] = s0.w;
        }

        float pd[4], acc[8];
#pragma unroll
        for (int c = 0; c < 4; ++c) pd[c] = 0.f;
#pragma unroll
        for (int j = 0; j < 8; ++j) acc[j] = 0.f;

        for (int c0 = 0; c0 < deg; c0 += CAP) {
            int cnt = min(CAP, deg - c0);
            int cnt4 = (cnt + 3) & ~3;

            // phase A: w = exp(leaky(e)) -> LDS, denominator partials in regs
            for (int i = lane; i < cnt4; i += 64) {
                if (i < cnt) {
                    int s = col[start + c0 + i];
                    colw[i] = s * HC;
                    float4 p = *reinterpret_cast<const float4*>(&ssrcb[(size_t)s * NH]);
                    float e[4];
                    e[0] = p.x + sd[0]; e[1] = p.y + sd[1];
                    e[2] = p.z + sd[2]; e[3] = p.w + sd[3];
#pragma unroll
                    for (int c = 0; c < 4; ++c) {
                        e[c] = fmaxf(e[c], NEG_SLOPE * e[c]);
                        float w = __expf(e[c]);
                        ew[c * EST + i] = w;
                        pd[c] += w;
                    }
                } else {
                    colw[i] = 0;
#pragma unroll
                    for (int c = 0; c < 4; ++c) ew[c * EST + i] = 0.f;
                }
            }

            // phase C: edge-parallel gather, 4 edges/iter, 2x16B loads per lane
            for (int i = 0; i < cnt4; i += 4) {
                int i0 = i + es, i1 = i + 2 + es;
                int o0 = colw[i0], o1 = colw[i1];
                float w0 = ew[hd * EST + i0], w1 = ew[hd * EST + i1];
                half8 v0 = *reinterpret_cast<const half8*>(hbase + o0 + cg8);
                half8 v1 = *reinterpret_cast<const half8*>(hbase + o1 + cg8);
#pragma unroll
                for (int j = 0; j < 8; ++j) acc[j] = fmaf((float)v0[j], w0, acc[j]);
#pragma unroll
                for (int j = 0; j < 8; ++j) acc[j] = fmaf((float)v1[j], w1, acc[j]);
            }
        }

        // denominator reduce (off the memory critical path)
#pragma unroll
        for (int off = 32; off > 0; off >>= 1)
#pragma unroll
            for (int c = 0; c < 4; ++c) pd[c] += __shfl_xor(pd[c], off);

        // reduce acc across edge slots
#pragma unroll
        for (int j = 0; j < 8; ++j) acc[j] += __shfl_xor(acc[j], 32);

        if (es == 0) {
            float inv = 1.0f / pd[hd];
            float4 b0 = *reinterpret_cast<const float4*>(&bias[cg8]);
            float4 b1 = *reinterpret_cast<const float4*>(&bias[cg8 + 4]);
            float bv[8] = {b0.x, b0.y, b0.z, b0.w, b1.x, b1.y, b1.z, b1.w};
            ushort_t o[8];
#pragma unroll
            for (int j = 0; j < 8; ++j) {
                float r = acc[j] * inv + bv[j];
                if (do_elu && r < 0.f) r = expm1f(r);
                o[j] = f2h_bits(r);
            }
            *reinterpret_cast<uint4*>(&outh[((size_t)b * NN + n) * HC + cg8]) =
                *reinterpret_cast<uint4*>(&o[0]);
        }
    }
}

// ---------------- launch ----------------

extern "C" void kernel_launch(void* const* d_in, const int* in_sizes, int n_in,
                              void* d_out, int out_size, void* d_ws, size_t ws_size,
                              hipStream_t stream) {
    const float* x      = (const float*)d_in[0];   // [2, NN, FIN]
    const int*   ei     = (const int*)d_in[1];     // [2, NE]
    const float* W1     = (const float*)d_in[2];   // [FIN, HC]
    const float* a_src1 = (const float*)d_in[3];
    const float* a_dst1 = (const float*)d_in[4];
    const float* b1     = (const float*)d_in[5];
    const float* W2     = (const float*)d_in[6];   // [HC, HC]
    const float* a_src2 = (const float*)d_in[7];
    const float* a_dst2 = (const float*)d_in[8];
    const float* b2     = (const float*)d_in[9];
    const float* Wf     = (const float*)d_in[10];  // [HC, CH]
    const float* bf     = (const float*)d_in[11];
    float* out = (float*)d_out;                    // [2, NN, CH]

    const int M2 = 2 * NN;
    float* ws = (float*)d_ws;
    float* Ssrc = ws;                              // M2*NH
    float* Sdst = Ssrc + (size_t)M2 * NH;          // M2*NH
    ushort_t* Hb16 = (ushort_t*)(Sdst + (size_t)M2 * NH);  // M2*HC f16 (gemm out)
    ushort_t* Ob16 = Hb16 + (size_t)M2 * HC;       // M2*HC f16 (agg out)
    ushort_t* Xb16 = Ob16 + (size_t)M2 * HC;       // M2*FIN f16
    ushort_t* Wt1  = Xb16 + (size_t)M2 * FIN;      // HC*FIN
    ushort_t* Wt2  = Wt1 + (size_t)HC * FIN;       // HC*HC
    ushort_t* Wtf  = Wt2 + (size_t)HC * HC;        // CH*HC
    int* counts = (int*)(Wtf + (size_t)CH * HC);
    int* rowptr = counts + NN;                     // NN+1
    int* cursor = rowptr + (NN + 1);
    int* colidx = cursor + NN;                     // ETOT
    int* bsum   = colidx + ETOT;                   // SCB
    int* bpre   = bsum + SCB;                      // SCB

    // ---- CSR build (parallel scan) ----
    k_zero_i32<<<(NN + 255) / 256, 256, 0, stream>>>(counts, NN);
    k_hist<<<(ETOT + 255) / 256, 256, 0, stream>>>(ei, counts);
    k_scan_part<<<SCB, 256, 0, stream>>>(counts, bsum);
    k_scan_top<<<1, 128, 0, stream>>>(bsum, bpre);
    k_scan_apply<<<SCB, 256, 0, stream>>>(counts, bpre, rowptr, cursor);
    k_scatter<<<(ETOT + 255) / 256, 256, 0, stream>>>(ei, cursor, colidx);

    // ---- fused setup: weight transposes + x convert ----
    k_setup<<<(SN4 + 255) / 256, 256, 0, stream>>>(x, W1, W2, Wf, Xb16, Wt1, Wt2, Wtf);

    const int gM128 = (M2 + 127) / 128;        // 313
    // layer 1 (scores fused into GEMM epilogue)
    k_gemm128<<<dim3(gM128, HC / 128), 256, 0, stream>>>(Xb16, Wt1, Hb16, a_src1, a_dst1,
                                                         Ssrc, Sdst, M2, FIN, HC);
    k_agg<<<AGG_BLOCKS, 256, 0, stream>>>(Hb16, Ssrc, Sdst, rowptr, colidx, b1, Ob16, 1);
    // layer 2
    k_gemm128<<<dim3(gM128, HC / 128), 256, 0, stream>>>(Ob16, Wt2, Hb16, a_src2, a_dst2,
                                                         Ssrc, Sdst, M2, HC, HC);
    k_agg<<<AGG_BLOCKS, 256, 0, stream>>>(Hb16, Ssrc, Sdst, rowptr, colidx, b2, Ob16, 0);
    // final projection (64-wide): f32 out + bias
    k_gemm_mfma<<<dim3((M2 + 63) / 64, CH / 64), 256, 0, stream>>>(Ob16, Wtf, out, bf, M2, HC, CH);
}

// Round 13
// 192.497 us; speedup vs baseline: 1.1505x; 1.1010x over previous
//
#include <hip/hip_runtime.h>
#include <math.h>

#define NN 20000          // nodes per graph
#define NE 320000         // edges (before self loops)
#define ETOT (NE + NN)    // edges + self loops
#define NH 4              // heads
#define CH 64             // channels per head
#define HC 256            // NH*CH
#define FIN 128           // layer-1 input features
#define NEG_SLOPE 0.2f
#define CAP 64            // edges per softmax chunk (multiple of 8)
#define EST 68            // ew stride in floats
#define SCB 79            // scan blocks: 79*256 >= NN

typedef unsigned short ushort_t;
typedef unsigned int uint_t;
typedef _Float16 half8 __attribute__((ext_vector_type(8)));
typedef float f32x4 __attribute__((ext_vector_type(4)));

__device__ __forceinline__ ushort_t f2h_bits(float f) {
    union { _Float16 h; ushort_t u; } c; c.h = (_Float16)f;
    return c.u;
}

// ---------------- CSR build ----------------

__global__ void k_zero_i32(int* __restrict__ p, int n) {
    int i = blockIdx.x * blockDim.x + threadIdx.x;
    if (i < n) p[i] = 0;
}

__global__ void k_hist(const int* __restrict__ ei, int* __restrict__ counts) {
    int e = blockIdx.x * blockDim.x + threadIdx.x;
    if (e >= ETOT) return;
    int d = (e < NE) ? ei[NE + e] : (e - NE);
    atomicAdd(&counts[d], 1);
}

// parallel scan: per-block reduce -> top scan -> per-block local scan + apply
__global__ void k_scan_part(const int* __restrict__ counts, int* __restrict__ bsum) {
    __shared__ int red[256];
    int t = threadIdx.x;
    int i = blockIdx.x * 256 + t;
    red[t] = (i < NN) ? counts[i] : 0;
    __syncthreads();
#pragma unroll
    for (int off = 128; off > 0; off >>= 1) {
        if (t < off) red[t] += red[t + off];
        __syncthreads();
    }
    if (t == 0) bsum[blockIdx.x] = red[0];
}

__global__ void k_scan_top(const int* __restrict__ bsum, int* __restrict__ bpre) {
    __shared__ int s[128];
    int t = threadIdx.x;
    int own = (t < SCB) ? bsum[t] : 0;
    s[t] = own;
    __syncthreads();
#pragma unroll
    for (int off = 1; off < 128; off <<= 1) {
        int v = (t >= off) ? s[t - off] : 0;
        __syncthreads();
        s[t] += v;
        __syncthreads();
    }
    if (t < SCB) bpre[t] = s[t] - own;   // exclusive block prefix
}

__global__ void k_scan_apply(const int* __restrict__ counts, const int* __restrict__ bpre,
                             int* __restrict__ rowptr, int* __restrict__ cursor) {
    __shared__ int s[256];
    int t = threadIdx.x;
    int i = blockIdx.x * 256 + t;
    int c = (i < NN) ? counts[i] : 0;
    s[t] = c;
    __syncthreads();
#pragma unroll
    for (int off = 1; off < 256; off <<= 1) {
        int v = (t >= off) ? s[t - off] : 0;
        __syncthreads();
        s[t] += v;
        __syncthreads();
    }
    int ex = s[t] - c + bpre[blockIdx.x];
    if (i < NN) { rowptr[i] = ex; cursor[i] = ex; }
    if (i == NN - 1) rowptr[NN] = ex + c;
}

__global__ void k_scatter(const int* __restrict__ ei, int* __restrict__ cursor,
                          int* __restrict__ col) {
    int e = blockIdx.x * blockDim.x + threadIdx.x;
    if (e >= ETOT) return;
    int s, d;
    if (e < NE) { s = ei[e]; d = ei[NE + e]; }
    else        { s = e - NE; d = s; }
    int pos = atomicAdd(&cursor[d], 1);
    col[pos] = s;
}

// ---------------- fused setup: weight transposes + x convert ----------------

#define SN1 (FIN * HC)                      // Wt1
#define SN2 (SN1 + HC * HC)                 // Wt2
#define SN3 (SN2 + HC * CH)                 // Wtf
#define SN4 (SN3 + (2 * NN * FIN) / 4)      // x convert (vec4)

__global__ void k_setup(const float* __restrict__ x, const float* __restrict__ W1,
                        const float* __restrict__ W2, const float* __restrict__ Wf,
                        ushort_t* __restrict__ Xh, ushort_t* __restrict__ Wt1,
                        ushort_t* __restrict__ Wt2, ushort_t* __restrict__ Wtf) {
    int i = blockIdx.x * blockDim.x + threadIdx.x;
    if (i < SN1) {
        int n = i / FIN, k = i - n * FIN;
        Wt1[i] = f2h_bits(W1[(size_t)k * HC + n]);
    } else if (i < SN2) {
        int j = i - SN1;
        int n = j / HC, k = j - n * HC;
        Wt2[j] = f2h_bits(W2[(size_t)k * HC + n]);
    } else if (i < SN3) {
        int j = i - SN2;
        int n = j / HC, k = j - n * HC;
        Wtf[j] = f2h_bits(Wf[(size_t)k * CH + n]);
    } else if (i < SN4) {
        int j = (i - SN3) * 4;
        float4 v = *reinterpret_cast<const float4*>(&x[j]);
        ushort4 u;
        u.x = f2h_bits(v.x); u.y = f2h_bits(v.y); u.z = f2h_bits(v.z); u.w = f2h_bits(v.w);
        *reinterpret_cast<ushort4*>(&Xh[j]) = u;
    }
}

// ---------------- 128x128 f16 MFMA GEMM + fused attention scores ----------------

__global__ __launch_bounds__(256) void k_gemm128(const ushort_t* __restrict__ A,
                                                 const ushort_t* __restrict__ Bt,
                                                 ushort_t* __restrict__ Ch,
                                                 const float* __restrict__ a_src,
                                                 const float* __restrict__ a_dst,
                                                 float* __restrict__ ssrc,
                                                 float* __restrict__ sdst,
                                                 int M, int K, int NC) {
    __shared__ ushort_t As[128 * 40];   // pad: 80B stride -> 2-way (free)
    __shared__ ushort_t Bs[128 * 40];
    int tid = threadIdx.x;
    int wave = tid >> 6, lane = tid & 63;
    int wr = wave >> 1, wc = wave & 1;
    int row0 = blockIdx.x * 128, col0 = blockIdx.y * 128;

    f32x4 acc[4][4];
#pragma unroll
    for (int i = 0; i < 4; ++i)
#pragma unroll
        for (int j = 0; j < 4; ++j) acc[i][j] = (f32x4){0.f, 0.f, 0.f, 0.f};

    int srow = tid >> 2;
    int sk8 = (tid & 3) * 8;
    int l15 = lane & 15, lk = (lane >> 4) * 8;

    int ra0 = min(row0 + srow, M - 1);
    int ra1 = min(row0 + 64 + srow, M - 1);

    for (int k0 = 0; k0 < K; k0 += 32) {
        uint4 a0 = *reinterpret_cast<const uint4*>(&A[(size_t)ra0 * K + k0 + sk8]);
        uint4 a1 = *reinterpret_cast<const uint4*>(&A[(size_t)ra1 * K + k0 + sk8]);
        uint4 b0 = *reinterpret_cast<const uint4*>(&Bt[(size_t)(col0 + srow) * K + k0 + sk8]);
        uint4 b1 = *reinterpret_cast<const uint4*>(&Bt[(size_t)(col0 + 64 + srow) * K + k0 + sk8]);
        __syncthreads();
        *reinterpret_cast<uint4*>(&As[srow * 40 + sk8]) = a0;
        *reinterpret_cast<uint4*>(&As[(64 + srow) * 40 + sk8]) = a1;
        *reinterpret_cast<uint4*>(&Bs[srow * 40 + sk8]) = b0;
        *reinterpret_cast<uint4*>(&Bs[(64 + srow) * 40 + sk8]) = b1;
        __syncthreads();

        half8 af[4], bf_[4];
#pragma unroll
        for (int m = 0; m < 4; ++m)
            af[m] = *reinterpret_cast<const half8*>(&As[(wr * 64 + m * 16 + l15) * 40 + lk]);
#pragma unroll
        for (int nf = 0; nf < 4; ++nf)
            bf_[nf] = *reinterpret_cast<const half8*>(&Bs[(wc * 64 + nf * 16 + l15) * 40 + lk]);
#pragma unroll
        for (int m = 0; m < 4; ++m)
#pragma unroll
            for (int nf = 0; nf < 4; ++nf)
                acc[m][nf] = __builtin_amdgcn_mfma_f32_16x16x32_f16(af[m], bf_[nf], acc[m][nf], 0, 0, 0);
    }

    // C store (f16)
#pragma unroll
    for (int m = 0; m < 4; ++m)
#pragma unroll
        for (int nf = 0; nf < 4; ++nf) {
            int colc = col0 + wc * 64 + nf * 16 + l15;
#pragma unroll
            for (int j = 0; j < 4; ++j) {
                int row = row0 + wr * 64 + m * 16 + (lane >> 4) * 4 + j;
                if (row < M) Ch[(size_t)row * NC + colc] = f2h_bits(acc[m][nf][j]);
            }
        }

    // fused scores: this wave's 64 cols = one full head
    if (ssrc) {
        int head = (col0 >> 6) + wc;
        float as4[4], ad4[4];
#pragma unroll
        for (int nf = 0; nf < 4; ++nf) {
            as4[nf] = a_src[head * 64 + nf * 16 + l15];
            ad4[nf] = a_dst[head * 64 + nf * 16 + l15];
        }
#pragma unroll
        for (int m = 0; m < 4; ++m)
#pragma unroll
            for (int j = 0; j < 4; ++j) {
                float ps = acc[m][0][j] * as4[0] + acc[m][1][j] * as4[1]
                         + acc[m][2][j] * as4[2] + acc[m][3][j] * as4[3];
                float pd = acc[m][0][j] * ad4[0] + acc[m][1][j] * ad4[1]
                         + acc[m][2][j] * ad4[2] + acc[m][3][j] * ad4[3];
#pragma unroll
                for (int off = 1; off < 16; off <<= 1) {
                    ps += __shfl_xor(ps, off);
                    pd += __shfl_xor(pd, off);
                }
                int row = row0 + wr * 64 + m * 16 + (lane >> 4) * 4 + j;
                if (l15 == 0 && row < M) {
                    ssrc[(size_t)row * NH + head] = ps;
                    sdst[(size_t)row * NH + head] = pd;
                }
            }
    }
}

// ---------------- 64x64 f16 MFMA GEMM (final projection, f32 out + bias) ----------------

__global__ __launch_bounds__(256) void k_gemm_mfma(const ushort_t* __restrict__ A,
                                                   const ushort_t* __restrict__ Bt,
                                                   float* __restrict__ Cf,
                                                   const float* __restrict__ bias,
                                                   int M, int K, int NC) {
    __shared__ ushort_t As[64][40];
    __shared__ ushort_t Bs[64][40];
    int tid = threadIdx.x;
    int wave = tid >> 6, lane = tid & 63;
    int wr = wave >> 1, wc = wave & 1;
    int row0 = blockIdx.x * 64, col0 = blockIdx.y * 64;

    f32x4 acc[2][2];
#pragma unroll
    for (int i = 0; i < 2; ++i)
#pragma unroll
        for (int j = 0; j < 2; ++j) acc[i][j] = (f32x4){0.f, 0.f, 0.f, 0.f};

    int sr = tid >> 2;
    int sk = (tid & 3) * 8;
    int l15 = lane & 15, lk = (lane >> 4) * 8;

    for (int k0 = 0; k0 < K; k0 += 32) {
        uint4 av = make_uint4(0, 0, 0, 0);
        int rowg = row0 + sr;
        if (rowg < M) av = *reinterpret_cast<const uint4*>(&A[(size_t)rowg * K + k0 + sk]);
        uint4 bv = *reinterpret_cast<const uint4*>(&Bt[(size_t)(col0 + sr) * K + k0 + sk]);
        __syncthreads();
        *reinterpret_cast<uint4*>(&As[sr][sk]) = av;
        *reinterpret_cast<uint4*>(&Bs[sr][sk]) = bv;
        __syncthreads();

        half8 a0 = *reinterpret_cast<const half8*>(&As[wr * 32 + l15][lk]);
        half8 a1 = *reinterpret_cast<const half8*>(&As[wr * 32 + 16 + l15][lk]);
        half8 b0 = *reinterpret_cast<const half8*>(&Bs[wc * 32 + l15][lk]);
        half8 b1 = *reinterpret_cast<const half8*>(&Bs[wc * 32 + 16 + l15][lk]);
        acc[0][0] = __builtin_amdgcn_mfma_f32_16x16x32_f16(a0, b0, acc[0][0], 0, 0, 0);
        acc[0][1] = __builtin_amdgcn_mfma_f32_16x16x32_f16(a0, b1, acc[0][1], 0, 0, 0);
        acc[1][0] = __builtin_amdgcn_mfma_f32_16x16x32_f16(a1, b0, acc[1][0], 0, 0, 0);
        acc[1][1] = __builtin_amdgcn_mfma_f32_16x16x32_f16(a1, b1, acc[1][1], 0, 0, 0);
    }

#pragma unroll
    for (int fr = 0; fr < 2; ++fr)
#pragma unroll
        for (int fc = 0; fc < 2; ++fc) {
            int colc = col0 + wc * 32 + fc * 16 + l15;
#pragma unroll
            for (int j = 0; j < 4; ++j) {
                int row = row0 + wr * 32 + fr * 16 + (lane >> 4) * 4 + j;
                if (row < M) Cf[(size_t)row * NC + colc] = acc[fr][fc][j] + bias[colc];
            }
        }
}

// ---------------- edge softmax + aggregation: one wave per (node, batch) ----------------
// Round-10 form (best measured: 47.6 us): flat dispatch, 4 waves/block,
// batch-sequential wave mapping (live gather set = one 20.5 MB h slab), no-max
// softmax (|e| <~ 20), pad-8 chunks, 8 edges/iter with 4x16B loads in flight.
// Plain __launch_bounds__ — forcing min-waves spilled in round 9. Persistent
// grid-stride regressed in round 12 (pass smearing grew the L2 set).

__global__ __launch_bounds__(256) void k_agg(const ushort_t* __restrict__ hb,  // [2*NN][HC] f16
                                             const float* __restrict__ ssrc,   // [2*NN][NH]
                                             const float* __restrict__ sdst,
                                             const int* __restrict__ rowptr,
                                             const int* __restrict__ col,
                                             const float* __restrict__ bias,
                                             ushort_t* __restrict__ outh,      // [2*NN][HC] f16
                                             int do_elu) {
    __shared__ int cols_lds[4][CAP];
    __shared__ float e_lds[4][4 * EST];
    int wave = threadIdx.x >> 6, lane = threadIdx.x & 63;
    int gw = blockIdx.x * 4 + wave;      // global wave id in [0, 2*NN)
    int b = (gw >= NN) ? 1 : 0;
    int n = gw - b * NN;
    int* colw = cols_lds[wave];
    float* ew = e_lds[wave];
    int start = rowptr[n];
    int deg = rowptr[n + 1] - start;
    int es = lane >> 5;          // edge slot
    int cg = lane & 31;          // channel group: ch [8cg, 8cg+8)
    int hd = cg >> 3;            // head of this lane's channels

    const ushort_t* hbase = hb + (size_t)b * NN * HC;
    const float* ssrcb = ssrc + (size_t)b * NN * NH;

    float sd[4];
    {
        float4 s0 = *reinterpret_cast<const float4*>(&sdst[((size_t)b * NN + n) * NH]);
        sd[0] = s0.x; sd[1] = s0.y; sd[2] = s0.z; sd[3] = s0.w;
    }

    float pd[4], acc[8];
#pragma unroll
    for (int c = 0; c < 4; ++c) pd[c] = 0.f;
#pragma unroll
    for (int j = 0; j < 8; ++j) acc[j] = 0.f;

    const int cg8 = cg * 8;

    for (int c0 = 0; c0 < deg; c0 += CAP) {
        int cnt = min(CAP, deg - c0);
        int cnt8 = (cnt + 7) & ~7;

        // phase A: w = exp(leaky(e)) -> LDS, denominator partials in regs
        for (int i = lane; i < cnt8; i += 64) {
            if (i < cnt) {
                int s = col[start + c0 + i];
                colw[i] = s * HC;
                float4 p = *reinterpret_cast<const float4*>(&ssrcb[(size_t)s * NH]);
                float e[4];
                e[0] = p.x + sd[0]; e[1] = p.y + sd[1]; e[2] = p.z + sd[2]; e[3] = p.w + sd[3];
#pragma unroll
                for (int c = 0; c < 4; ++c) {
                    e[c] = fmaxf(e[c], NEG_SLOPE * e[c]);
                    float w = __expf(e[c]);
                    ew[c * EST + i] = w;
                    pd[c] += w;
                }
            } else {
                colw[i] = 0;
#pragma unroll
                for (int c = 0; c < 4; ++c) ew[c * EST + i] = 0.f;
            }
        }

        // phase C: edge-parallel gather, 8 edges/iter, 4x16B loads in flight per lane
        for (int i = 0; i < cnt8; i += 8) {
            int i0 = i + es, i1 = i + 2 + es, i2 = i + 4 + es, i3 = i + 6 + es;
            int o0 = colw[i0], o1 = colw[i1], o2 = colw[i2], o3 = colw[i3];
            float w0 = ew[hd * EST + i0], w1 = ew[hd * EST + i1];
            float w2 = ew[hd * EST + i2], w3 = ew[hd * EST + i3];
            half8 v0 = *reinterpret_cast<const half8*>(hbase + o0 + cg8);
            half8 v1 = *reinterpret_cast<const half8*>(hbase + o1 + cg8);
            half8 v2 = *reinterpret_cast<const half8*>(hbase + o2 + cg8);
            half8 v3 = *reinterpret_cast<const half8*>(hbase + o3 + cg8);
#pragma unroll
            for (int j = 0; j < 8; ++j) acc[j] = fmaf((float)v0[j], w0, acc[j]);
#pragma unroll
            for (int j = 0; j < 8; ++j) acc[j] = fmaf((float)v1[j], w1, acc[j]);
#pragma unroll
            for (int j = 0; j < 8; ++j) acc[j] = fmaf((float)v2[j], w2, acc[j]);
#pragma unroll
            for (int j = 0; j < 8; ++j) acc[j] = fmaf((float)v3[j], w3, acc[j]);
        }
    }

    // denominator reduce (off the memory critical path)
#pragma unroll
    for (int off = 32; off > 0; off >>= 1)
#pragma unroll
        for (int c = 0; c < 4; ++c) pd[c] += __shfl_xor(pd[c], off);

    // reduce acc across edge slots
#pragma unroll
    for (int j = 0; j < 8; ++j) acc[j] += __shfl_xor(acc[j], 32);

    if (es == 0) {
        float inv = 1.0f / pd[hd];
        float4 b0 = *reinterpret_cast<const float4*>(&bias[cg8]);
        float4 b1 = *reinterpret_cast<const float4*>(&bias[cg8 + 4]);
        float bv[8] = {b0.x, b0.y, b0.z, b0.w, b1.x, b1.y, b1.z, b1.w};
        ushort_t o[8];
#pragma unroll
        for (int j = 0; j < 8; ++j) {
            float r = acc[j] * inv + bv[j];
            if (do_elu && r < 0.f) r = expm1f(r);
            o[j] = f2h_bits(r);
        }
        *reinterpret_cast<uint4*>(&outh[((size_t)b * NN + n) * HC + cg8]) =
            *reinterpret_cast<uint4*>(&o[0]);
    }
}

// ---------------- launch ----------------

extern "C" void kernel_launch(void* const* d_in, const int* in_sizes, int n_in,
                              void* d_out, int out_size, void* d_ws, size_t ws_size,
                              hipStream_t stream) {
    const float* x      = (const float*)d_in[0];   // [2, NN, FIN]
    const int*   ei     = (const int*)d_in[1];     // [2, NE]
    const float* W1     = (const float*)d_in[2];   // [FIN, HC]
    const float* a_src1 = (const float*)d_in[3];
    const float* a_dst1 = (const float*)d_in[4];
    const float* b1     = (const float*)d_in[5];
    const float* W2     = (const float*)d_in[6];   // [HC, HC]
    const float* a_src2 = (const float*)d_in[7];
    const float* a_dst2 = (const float*)d_in[8];
    const float* b2     = (const float*)d_in[9];
    const float* Wf     = (const float*)d_in[10];  // [HC, CH]
    const float* bf     = (const float*)d_in[11];
    float* out = (float*)d_out;                    // [2, NN, CH]

    const int M2 = 2 * NN;
    float* ws = (float*)d_ws;
    float* Ssrc = ws;                              // M2*NH
    float* Sdst = Ssrc + (size_t)M2 * NH;          // M2*NH
    ushort_t* Hb16 = (ushort_t*)(Sdst + (size_t)M2 * NH);  // M2*HC f16 (gemm out)
    ushort_t* Ob16 = Hb16 + (size_t)M2 * HC;       // M2*HC f16 (agg out)
    ushort_t* Xb16 = Ob16 + (size_t)M2 * HC;       // M2*FIN f16
    ushort_t* Wt1  = Xb16 + (size_t)M2 * FIN;      // HC*FIN
    ushort_t* Wt2  = Wt1 + (size_t)HC * FIN;       // HC*HC
    ushort_t* Wtf  = Wt2 + (size_t)HC * HC;        // CH*HC
    int* counts = (int*)(Wtf + (size_t)CH * HC);
    int* rowptr = counts + NN;                     // NN+1
    int* cursor = rowptr + (NN + 1);
    int* colidx = cursor + NN;                     // ETOT
    int* bsum   = colidx + ETOT;                   // SCB
    int* bpre   = bsum + SCB;                      // SCB

    // ---- CSR build (parallel scan) ----
    k_zero_i32<<<(NN + 255) / 256, 256, 0, stream>>>(counts, NN);
    k_hist<<<(ETOT + 255) / 256, 256, 0, stream>>>(ei, counts);
    k_scan_part<<<SCB, 256, 0, stream>>>(counts, bsum);
    k_scan_top<<<1, 128, 0, stream>>>(bsum, bpre);
    k_scan_apply<<<SCB, 256, 0, stream>>>(counts, bpre, rowptr, cursor);
    k_scatter<<<(ETOT + 255) / 256, 256, 0, stream>>>(ei, cursor, colidx);

    // ---- fused setup: weight transposes + x convert ----
    k_setup<<<(SN4 + 255) / 256, 256, 0, stream>>>(x, W1, W2, Wf, Xb16, Wt1, Wt2, Wtf);

    const int gM128 = (M2 + 127) / 128;        // 313
    const int gAgg = M2 / 4;                   // 10000 blocks x 4 waves
    // layer 1 (scores fused into GEMM epilogue)
    k_gemm128<<<dim3(gM128, HC / 128), 256, 0, stream>>>(Xb16, Wt1, Hb16, a_src1, a_dst1,
                                                         Ssrc, Sdst, M2, FIN, HC);
    k_agg<<<gAgg, 256, 0, stream>>>(Hb16, Ssrc, Sdst, rowptr, colidx, b1, Ob16, 1);
    // layer 2
    k_gemm128<<<dim3(gM128, HC / 128), 256, 0, stream>>>(Ob16, Wt2, Hb16, a_src2, a_dst2,
                                                         Ssrc, Sdst, M2, HC, HC);
    k_agg<<<gAgg, 256, 0, stream>>>(Hb16, Ssrc, Sdst, rowptr, colidx, b2, Ob16, 0);
    // final projection (64-wide): f32 out + bias
    k_gemm_mfma<<<dim3((M2 + 63) / 64, CH / 64), 256, 0, stream>>>(Ob16, Wtf, out, bf, M2, HC, CH);
}

// Round 14
// 187.736 us; speedup vs baseline: 1.1797x; 1.0254x over previous
//
#include <hip/hip_runtime.h>
#include <math.h>

#define NN 20000          // nodes per graph
#define NE 320000         // edges (before self loops)
#define ETOT (NE + NN)    // edges + self loops
#define NH 4              // heads
#define CH 64             // channels per head
#define HC 256            // NH*CH
#define FIN 128           // layer-1 input features
#define NEG_SLOPE 0.2f
#define CAP 64            // edges per softmax chunk (multiple of 8)
#define EST 68            // ew stride in floats
#define SCB 79            // scan blocks: 79*256 >= NN

typedef unsigned short ushort_t;
typedef unsigned int uint_t;
typedef _Float16 half8 __attribute__((ext_vector_type(8)));
typedef float f32x4 __attribute__((ext_vector_type(4)));

__device__ __forceinline__ ushort_t f2h_bits(float f) {
    union { _Float16 h; ushort_t u; } c; c.h = (_Float16)f;
    return c.u;
}

// fused f16->f32 convert + FMA: acc_lo += f16lo(word)*w ; acc_hi += f16hi(word)*w
__device__ __forceinline__ void fma_mix_pair(float& alo, float& ahi, uint_t word, float w) {
    asm("v_fma_mix_f32 %0, %1, %2, %0 op_sel:[0,0,0] op_sel_hi:[1,0,0]"
        : "+v"(alo) : "v"(word), "v"(w));
    asm("v_fma_mix_f32 %0, %1, %2, %0 op_sel:[1,0,0] op_sel_hi:[1,0,0]"
        : "+v"(ahi) : "v"(word), "v"(w));
}

// ---------------- CSR build ----------------

__global__ void k_hist(const int* __restrict__ ei, int* __restrict__ counts) {
    int e = blockIdx.x * blockDim.x + threadIdx.x;
    if (e >= ETOT) return;
    int d = (e < NE) ? ei[NE + e] : (e - NE);
    atomicAdd(&counts[d], 1);
}

// parallel scan: per-block reduce -> top scan -> per-block local scan + apply
__global__ void k_scan_part(const int* __restrict__ counts, int* __restrict__ bsum) {
    __shared__ int red[256];
    int t = threadIdx.x;
    int i = blockIdx.x * 256 + t;
    red[t] = (i < NN) ? counts[i] : 0;
    __syncthreads();
#pragma unroll
    for (int off = 128; off > 0; off >>= 1) {
        if (t < off) red[t] += red[t + off];
        __syncthreads();
    }
    if (t == 0) bsum[blockIdx.x] = red[0];
}

__global__ void k_scan_top(const int* __restrict__ bsum, int* __restrict__ bpre) {
    __shared__ int s[128];
    int t = threadIdx.x;
    int own = (t < SCB) ? bsum[t] : 0;
    s[t] = own;
    __syncthreads();
#pragma unroll
    for (int off = 1; off < 128; off <<= 1) {
        int v = (t >= off) ? s[t - off] : 0;
        __syncthreads();
        s[t] += v;
        __syncthreads();
    }
    if (t < SCB) bpre[t] = s[t] - own;   // exclusive block prefix
}

__global__ void k_scan_apply(const int* __restrict__ counts, const int* __restrict__ bpre,
                             int* __restrict__ rowptr, int* __restrict__ cursor) {
    __shared__ int s[256];
    int t = threadIdx.x;
    int i = blockIdx.x * 256 + t;
    int c = (i < NN) ? counts[i] : 0;
    s[t] = c;
    __syncthreads();
#pragma unroll
    for (int off = 1; off < 256; off <<= 1) {
        int v = (t >= off) ? s[t - off] : 0;
        __syncthreads();
        s[t] += v;
        __syncthreads();
    }
    int ex = s[t] - c + bpre[blockIdx.x];
    if (i < NN) { rowptr[i] = ex; cursor[i] = ex; }
    if (i == NN - 1) rowptr[NN] = ex + c;
}

__global__ void k_scatter(const int* __restrict__ ei, int* __restrict__ cursor,
                          int* __restrict__ col) {
    int e = blockIdx.x * blockDim.x + threadIdx.x;
    if (e >= ETOT) return;
    int s, d;
    if (e < NE) { s = ei[e]; d = ei[NE + e]; }
    else        { s = e - NE; d = s; }
    int pos = atomicAdd(&cursor[d], 1);
    col[pos] = s;
}

// ---------------- fused setup: weight transposes + x convert ----------------

#define SN1 (FIN * HC)                      // Wt1
#define SN2 (SN1 + HC * HC)                 // Wt2
#define SN3 (SN2 + HC * CH)                 // Wtf
#define SN4 (SN3 + (2 * NN * FIN) / 4)      // x convert (vec4)

__global__ void k_setup(const float* __restrict__ x, const float* __restrict__ W1,
                        const float* __restrict__ W2, const float* __restrict__ Wf,
                        ushort_t* __restrict__ Xh, ushort_t* __restrict__ Wt1,
                        ushort_t* __restrict__ Wt2, ushort_t* __restrict__ Wtf) {
    int i = blockIdx.x * blockDim.x + threadIdx.x;
    if (i < SN1) {
        int n = i / FIN, k = i - n * FIN;
        Wt1[i] = f2h_bits(W1[(size_t)k * HC + n]);
    } else if (i < SN2) {
        int j = i - SN1;
        int n = j / HC, k = j - n * HC;
        Wt2[j] = f2h_bits(W2[(size_t)k * HC + n]);
    } else if (i < SN3) {
        int j = i - SN2;
        int n = j / HC, k = j - n * HC;
        Wtf[j] = f2h_bits(Wf[(size_t)k * CH + n]);
    } else if (i < SN4) {
        int j = (i - SN3) * 4;
        float4 v = *reinterpret_cast<const float4*>(&x[j]);
        ushort4 u;
        u.x = f2h_bits(v.x); u.y = f2h_bits(v.y); u.z = f2h_bits(v.z); u.w = f2h_bits(v.w);
        *reinterpret_cast<ushort4*>(&Xh[j]) = u;
    }
}

// ---------------- 128x128 f16 MFMA GEMM + fused attention scores ----------------

__global__ __launch_bounds__(256) void k_gemm128(const ushort_t* __restrict__ A,
                                                 const ushort_t* __restrict__ Bt,
                                                 ushort_t* __restrict__ Ch,
                                                 const float* __restrict__ a_src,
                                                 const float* __restrict__ a_dst,
                                                 float* __restrict__ ssrc,
                                                 float* __restrict__ sdst,
                                                 int M, int K, int NC) {
    __shared__ ushort_t As[128 * 40];   // pad: 80B stride -> 2-way (free)
    __shared__ ushort_t Bs[128 * 40];
    int tid = threadIdx.x;
    int wave = tid >> 6, lane = tid & 63;
    int wr = wave >> 1, wc = wave & 1;
    int row0 = blockIdx.x * 128, col0 = blockIdx.y * 128;

    f32x4 acc[4][4];
#pragma unroll
    for (int i = 0; i < 4; ++i)
#pragma unroll
        for (int j = 0; j < 4; ++j) acc[i][j] = (f32x4){0.f, 0.f, 0.f, 0.f};

    int srow = tid >> 2;
    int sk8 = (tid & 3) * 8;
    int l15 = lane & 15, lk = (lane >> 4) * 8;

    int ra0 = min(row0 + srow, M - 1);
    int ra1 = min(row0 + 64 + srow, M - 1);

    for (int k0 = 0; k0 < K; k0 += 32) {
        uint4 a0 = *reinterpret_cast<const uint4*>(&A[(size_t)ra0 * K + k0 + sk8]);
        uint4 a1 = *reinterpret_cast<const uint4*>(&A[(size_t)ra1 * K + k0 + sk8]);
        uint4 b0 = *reinterpret_cast<const uint4*>(&Bt[(size_t)(col0 + srow) * K + k0 + sk8]);
        uint4 b1 = *reinterpret_cast<const uint4*>(&Bt[(size_t)(col0 + 64 + srow) * K + k0 + sk8]);
        __syncthreads();
        *reinterpret_cast<uint4*>(&As[srow * 40 + sk8]) = a0;
        *reinterpret_cast<uint4*>(&As[(64 + srow) * 40 + sk8]) = a1;
        *reinterpret_cast<uint4*>(&Bs[srow * 40 + sk8]) = b0;
        *reinterpret_cast<uint4*>(&Bs[(64 + srow) * 40 + sk8]) = b1;
        __syncthreads();

        half8 af[4], bf_[4];
#pragma unroll
        for (int m = 0; m < 4; ++m)
            af[m] = *reinterpret_cast<const half8*>(&As[(wr * 64 + m * 16 + l15) * 40 + lk]);
#pragma unroll
        for (int nf = 0; nf < 4; ++nf)
            bf_[nf] = *reinterpret_cast<const half8*>(&Bs[(wc * 64 + nf * 16 + l15) * 40 + lk]);
#pragma unroll
        for (int m = 0; m < 4; ++m)
#pragma unroll
            for (int nf = 0; nf < 4; ++nf)
                acc[m][nf] = __builtin_amdgcn_mfma_f32_16x16x32_f16(af[m], bf_[nf], acc[m][nf], 0, 0, 0);
    }

    // C store (f16)
#pragma unroll
    for (int m = 0; m < 4; ++m)
#pragma unroll
        for (int nf = 0; nf < 4; ++nf) {
            int colc = col0 + wc * 64 + nf * 16 + l15;
#pragma unroll
            for (int j = 0; j < 4; ++j) {
                int row = row0 + wr * 64 + m * 16 + (lane >> 4) * 4 + j;
                if (row < M) Ch[(size_t)row * NC + colc] = f2h_bits(acc[m][nf][j]);
            }
        }

    // fused scores: this wave's 64 cols = one full head
    if (ssrc) {
        int head = (col0 >> 6) + wc;
        float as4[4], ad4[4];
#pragma unroll
        for (int nf = 0; nf < 4; ++nf) {
            as4[nf] = a_src[head * 64 + nf * 16 + l15];
            ad4[nf] = a_dst[head * 64 + nf * 16 + l15];
        }
#pragma unroll
        for (int m = 0; m < 4; ++m)
#pragma unroll
            for (int j = 0; j < 4; ++j) {
                float ps = acc[m][0][j] * as4[0] + acc[m][1][j] * as4[1]
                         + acc[m][2][j] * as4[2] + acc[m][3][j] * as4[3];
                float pd = acc[m][0][j] * ad4[0] + acc[m][1][j] * ad4[1]
                         + acc[m][2][j] * ad4[2] + acc[m][3][j] * ad4[3];
#pragma unroll
                for (int off = 1; off < 16; off <<= 1) {
                    ps += __shfl_xor(ps, off);
                    pd += __shfl_xor(pd, off);
                }
                int row = row0 + wr * 64 + m * 16 + (lane >> 4) * 4 + j;
                if (l15 == 0 && row < M) {
                    ssrc[(size_t)row * NH + head] = ps;
                    sdst[(size_t)row * NH + head] = pd;
                }
            }
    }
}

// ---------------- 64x64 f16 MFMA GEMM (final projection, f32 out + bias) ----------------

__global__ __launch_bounds__(256) void k_gemm_mfma(const ushort_t* __restrict__ A,
                                                   const ushort_t* __restrict__ Bt,
                                                   float* __restrict__ Cf,
                                                   const float* __restrict__ bias,
                                                   int M, int K, int NC) {
    __shared__ ushort_t As[64][40];
    __shared__ ushort_t Bs[64][40];
    int tid = threadIdx.x;
    int wave = tid >> 6, lane = tid & 63;
    int wr = wave >> 1, wc = wave & 1;
    int row0 = blockIdx.x * 64, col0 = blockIdx.y * 64;

    f32x4 acc[2][2];
#pragma unroll
    for (int i = 0; i < 2; ++i)
#pragma unroll
        for (int j = 0; j < 2; ++j) acc[i][j] = (f32x4){0.f, 0.f, 0.f, 0.f};

    int sr = tid >> 2;
    int sk = (tid & 3) * 8;
    int l15 = lane & 15, lk = (lane >> 4) * 8;

    for (int k0 = 0; k0 < K; k0 += 32) {
        uint4 av = make_uint4(0, 0, 0, 0);
        int rowg = row0 + sr;
        if (rowg < M) av = *reinterpret_cast<const uint4*>(&A[(size_t)rowg * K + k0 + sk]);
        uint4 bv = *reinterpret_cast<const uint4*>(&Bt[(size_t)(col0 + sr) * K + k0 + sk]);
        __syncthreads();
        *reinterpret_cast<uint4*>(&As[sr][sk]) = av;
        *reinterpret_cast<uint4*>(&Bs[sr][sk]) = bv;
        __syncthreads();

        half8 a0 = *reinterpret_cast<const half8*>(&As[wr * 32 + l15][lk]);
        half8 a1 = *reinterpret_cast<const half8*>(&As[wr * 32 + 16 + l15][lk]);
        half8 b0 = *reinterpret_cast<const half8*>(&Bs[wc * 32 + l15][lk]);
        half8 b1 = *reinterpret_cast<const half8*>(&Bs[wc * 32 + 16 + l15][lk]);
        acc[0][0] = __builtin_amdgcn_mfma_f32_16x16x32_f16(a0, b0, acc[0][0], 0, 0, 0);
        acc[0][1] = __builtin_amdgcn_mfma_f32_16x16x32_f16(a0, b1, acc[0][1], 0, 0, 0);
        acc[1][0] = __builtin_amdgcn_mfma_f32_16x16x32_f16(a1, b0, acc[1][0], 0, 0, 0);
        acc[1][1] = __builtin_amdgcn_mfma_f32_16x16x32_f16(a1, b1, acc[1][1], 0, 0, 0);
    }

#pragma unroll
    for (int fr = 0; fr < 2; ++fr)
#pragma unroll
        for (int fc = 0; fc < 2; ++fc) {
            int colc = col0 + wc * 32 + fc * 16 + l15;
#pragma unroll
            for (int j = 0; j < 4; ++j) {
                int row = row0 + wr * 32 + fr * 16 + (lane >> 4) * 4 + j;
                if (row < M) Cf[(size_t)row * NC + colc] = acc[fr][fc][j] + bias[colc];
            }
        }
}

// ---------------- edge softmax + aggregation: one wave per (node, batch) ----------------
// Round-10 form (best measured: 47.6 us) + v_fma_mix_f32 gather core.
// Flat dispatch, 4 waves/block, batch-sequential wave mapping, no-max softmax,
// pad-8 chunks, 8 edges/iter with 4x16B loads in flight. Plain __launch_bounds__ —
// forcing min-waves spilled (round 9). Persistent grid regressed (round 12).

__global__ __launch_bounds__(256) void k_agg(const ushort_t* __restrict__ hb,  // [2*NN][HC] f16
                                             const float* __restrict__ ssrc,   // [2*NN][NH]
                                             const float* __restrict__ sdst,
                                             const int* __restrict__ rowptr,
                                             const int* __restrict__ col,
                                             const float* __restrict__ bias,
                                             ushort_t* __restrict__ outh,      // [2*NN][HC] f16
                                             int do_elu) {
    __shared__ int cols_lds[4][CAP];
    __shared__ float e_lds[4][4 * EST];
    int wave = threadIdx.x >> 6, lane = threadIdx.x & 63;
    int gw = blockIdx.x * 4 + wave;      // global wave id in [0, 2*NN)
    int b = (gw >= NN) ? 1 : 0;
    int n = gw - b * NN;
    int* colw = cols_lds[wave];
    float* ew = e_lds[wave];
    int start = rowptr[n];
    int deg = rowptr[n + 1] - start;
    int es = lane >> 5;          // edge slot
    int cg = lane & 31;          // channel group: ch [8cg, 8cg+8)
    int hd = cg >> 3;            // head of this lane's channels

    const ushort_t* hbase = hb + (size_t)b * NN * HC;
    const float* ssrcb = ssrc + (size_t)b * NN * NH;

    float sd[4];
    {
        float4 s0 = *reinterpret_cast<const float4*>(&sdst[((size_t)b * NN + n) * NH]);
        sd[0] = s0.x; sd[1] = s0.y; sd[2] = s0.z; sd[3] = s0.w;
    }

    float pd[4], acc[8];
#pragma unroll
    for (int c = 0; c < 4; ++c) pd[c] = 0.f;
#pragma unroll
    for (int j = 0; j < 8; ++j) acc[j] = 0.f;

    const int cg8 = cg * 8;

    for (int c0 = 0; c0 < deg; c0 += CAP) {
        int cnt = min(CAP, deg - c0);
        int cnt8 = (cnt + 7) & ~7;

        // phase A: w = exp(leaky(e)) -> LDS, denominator partials in regs
        for (int i = lane; i < cnt8; i += 64) {
            if (i < cnt) {
                int s = col[start + c0 + i];
                colw[i] = s * HC;
                float4 p = *reinterpret_cast<const float4*>(&ssrcb[(size_t)s * NH]);
                float e[4];
                e[0] = p.x + sd[0]; e[1] = p.y + sd[1]; e[2] = p.z + sd[2]; e[3] = p.w + sd[3];
#pragma unroll
                for (int c = 0; c < 4; ++c) {
                    e[c] = fmaxf(e[c], NEG_SLOPE * e[c]);
                    float w = __expf(e[c]);
                    ew[c * EST + i] = w;
                    pd[c] += w;
                }
            } else {
                colw[i] = 0;
#pragma unroll
                for (int c = 0; c < 4; ++c) ew[c * EST + i] = 0.f;
            }
        }

        // phase C: edge-parallel gather, 8 edges/iter, 4x16B loads in flight per lane,
        // fused cvt+fma via v_fma_mix_f32
        for (int i = 0; i < cnt8; i += 8) {
            int i0 = i + es, i1 = i + 2 + es, i2 = i + 4 + es, i3 = i + 6 + es;
            int o0 = colw[i0], o1 = colw[i1], o2 = colw[i2], o3 = colw[i3];
            float w0 = ew[hd * EST + i0], w1 = ew[hd * EST + i1];
            float w2 = ew[hd * EST + i2], w3 = ew[hd * EST + i3];
            uint4 u0 = *reinterpret_cast<const uint4*>(hbase + o0 + cg8);
            uint4 u1 = *reinterpret_cast<const uint4*>(hbase + o1 + cg8);
            uint4 u2 = *reinterpret_cast<const uint4*>(hbase + o2 + cg8);
            uint4 u3 = *reinterpret_cast<const uint4*>(hbase + o3 + cg8);
            fma_mix_pair(acc[0], acc[1], u0.x, w0);
            fma_mix_pair(acc[2], acc[3], u0.y, w0);
            fma_mix_pair(acc[4], acc[5], u0.z, w0);
            fma_mix_pair(acc[6], acc[7], u0.w, w0);
            fma_mix_pair(acc[0], acc[1], u1.x, w1);
            fma_mix_pair(acc[2], acc[3], u1.y, w1);
            fma_mix_pair(acc[4], acc[5], u1.z, w1);
            fma_mix_pair(acc[6], acc[7], u1.w, w1);
            fma_mix_pair(acc[0], acc[1], u2.x, w2);
            fma_mix_pair(acc[2], acc[3], u2.y, w2);
            fma_mix_pair(acc[4], acc[5], u2.z, w2);
            fma_mix_pair(acc[6], acc[7], u2.w, w2);
            fma_mix_pair(acc[0], acc[1], u3.x, w3);
            fma_mix_pair(acc[2], acc[3], u3.y, w3);
            fma_mix_pair(acc[4], acc[5], u3.z, w3);
            fma_mix_pair(acc[6], acc[7], u3.w, w3);
        }
    }

    // denominator reduce (off the memory critical path)
#pragma unroll
    for (int off = 32; off > 0; off >>= 1)
#pragma unroll
        for (int c = 0; c < 4; ++c) pd[c] += __shfl_xor(pd[c], off);

    // reduce acc across edge slots
#pragma unroll
    for (int j = 0; j < 8; ++j) acc[j] += __shfl_xor(acc[j], 32);

    if (es == 0) {
        float inv = 1.0f / pd[hd];
        float4 b0 = *reinterpret_cast<const float4*>(&bias[cg8]);
        float4 b1 = *reinterpret_cast<const float4*>(&bias[cg8 + 4]);
        float bv[8] = {b0.x, b0.y, b0.z, b0.w, b1.x, b1.y, b1.z, b1.w};
        ushort_t o[8];
#pragma unroll
        for (int j = 0; j < 8; ++j) {
            float r = acc[j] * inv + bv[j];
            if (do_elu && r < 0.f) r = expm1f(r);
            o[j] = f2h_bits(r);
        }
        *reinterpret_cast<uint4*>(&outh[((size_t)b * NN + n) * HC + cg8]) =
            *reinterpret_cast<uint4*>(&o[0]);
    }
}

// ---------------- launch ----------------

extern "C" void kernel_launch(void* const* d_in, const int* in_sizes, int n_in,
                              void* d_out, int out_size, void* d_ws, size_t ws_size,
                              hipStream_t stream) {
    const float* x      = (const float*)d_in[0];   // [2, NN, FIN]
    const int*   ei     = (const int*)d_in[1];     // [2, NE]
    const float* W1     = (const float*)d_in[2];   // [FIN, HC]
    const float* a_src1 = (const float*)d_in[3];
    const float* a_dst1 = (const float*)d_in[4];
    const float* b1     = (const float*)d_in[5];
    const float* W2     = (const float*)d_in[6];   // [HC, HC]
    const float* a_src2 = (const float*)d_in[7];
    const float* a_dst2 = (const float*)d_in[8];
    const float* b2     = (const float*)d_in[9];
    const float* Wf     = (const float*)d_in[10];  // [HC, CH]
    const float* bf     = (const float*)d_in[11];
    float* out = (float*)d_out;                    // [2, NN, CH]

    const int M2 = 2 * NN;
    float* ws = (float*)d_ws;
    float* Ssrc = ws;                              // M2*NH
    float* Sdst = Ssrc + (size_t)M2 * NH;          // M2*NH
    ushort_t* Hb16 = (ushort_t*)(Sdst + (size_t)M2 * NH);  // M2*HC f16 (gemm out)
    ushort_t* Ob16 = Hb16 + (size_t)M2 * HC;       // M2*HC f16 (agg out)
    ushort_t* Xb16 = Ob16 + (size_t)M2 * HC;       // M2*FIN f16
    ushort_t* Wt1  = Xb16 + (size_t)M2 * FIN;      // HC*FIN
    ushort_t* Wt2  = Wt1 + (size_t)HC * FIN;       // HC*HC
    ushort_t* Wtf  = Wt2 + (size_t)HC * HC;        // CH*HC
    int* counts = (int*)(Wtf + (size_t)CH * HC);
    int* rowptr = counts + NN;                     // NN+1
    int* cursor = rowptr + (NN + 1);
    int* colidx = cursor + NN;                     // ETOT
    int* bsum   = colidx + ETOT;                   // SCB
    int* bpre   = bsum + SCB;                      // SCB

    // ---- CSR build (parallel scan) ----
    hipMemsetAsync(counts, 0, (size_t)NN * sizeof(int), stream);
    k_hist<<<(ETOT + 255) / 256, 256, 0, stream>>>(ei, counts);
    k_scan_part<<<SCB, 256, 0, stream>>>(counts, bsum);
    k_scan_top<<<1, 128, 0, stream>>>(bsum, bpre);
    k_scan_apply<<<SCB, 256, 0, stream>>>(counts, bpre, rowptr, cursor);
    k_scatter<<<(ETOT + 255) / 256, 256, 0, stream>>>(ei, cursor, colidx);

    // ---- fused setup: weight transposes + x convert ----
    k_setup<<<(SN4 + 255) / 256, 256, 0, stream>>>(x, W1, W2, Wf, Xb16, Wt1, Wt2, Wtf);

    const int gM128 = (M2 + 127) / 128;        // 313
    const int gAgg = M2 / 4;                   // 10000 blocks x 4 waves
    // layer 1 (scores fused into GEMM epilogue)
    k_gemm128<<<dim3(gM128, HC / 128), 256, 0, stream>>>(Xb16, Wt1, Hb16, a_src1, a_dst1,
                                                         Ssrc, Sdst, M2, FIN, HC);
    k_agg<<<gAgg, 256, 0, stream>>>(Hb16, Ssrc, Sdst, rowptr, colidx, b1, Ob16, 1);
    // layer 2
    k_gemm128<<<dim3(gM128, HC / 128), 256, 0, stream>>>(Ob16, Wt2, Hb16, a_src2, a_dst2,
                                                         Ssrc, Sdst, M2, HC, HC);
    k_agg<<<gAgg, 256, 0, stream>>>(Hb16, Ssrc, Sdst, rowptr, colidx, b2, Ob16, 0);
    // final projection (64-wide): f32 out + bias
    k_gemm_mfma<<<dim3((M2 + 63) / 64, CH / 64), 256, 0, stream>>>(Ob16, Wtf, out, bf, M2, HC, CH);
}

// Round 15
// 184.776 us; speedup vs baseline: 1.1986x; 1.0160x over previous
//
#include <hip/hip_runtime.h>
#include <math.h>

#define NN 20000          // nodes per graph
#define NE 320000         // edges (before self loops)
#define ETOT (NE + NN)    // edges + self loops
#define NH 4              // heads
#define CH 64             // channels per head
#define HC 256            // NH*CH
#define FIN 128           // layer-1 input features
#define NEG_SLOPE 0.2f
#define CAP 64            // edges per softmax chunk (multiple of 8)
#define EST 80            // ew stride in floats (80%32=16 -> <=2-way conflicts, free)
#define SCB 79            // scan blocks: 79*256 >= NN

typedef unsigned short ushort_t;
typedef unsigned int uint_t;
typedef _Float16 half8 __attribute__((ext_vector_type(8)));
typedef float f32x4 __attribute__((ext_vector_type(4)));

__device__ __forceinline__ ushort_t f2h_bits(float f) {
    union { _Float16 h; ushort_t u; } c; c.h = (_Float16)f;
    return c.u;
}

// fused f16->f32 convert + FMA: acc_lo += f16lo(word)*w ; acc_hi += f16hi(word)*w
__device__ __forceinline__ void fma_mix_pair(float& alo, float& ahi, uint_t word, float w) {
    asm("v_fma_mix_f32 %0, %1, %2, %0 op_sel:[0,0,0] op_sel_hi:[1,0,0]"
        : "+v"(alo) : "v"(word), "v"(w));
    asm("v_fma_mix_f32 %0, %1, %2, %0 op_sel:[1,0,0] op_sel_hi:[1,0,0]"
        : "+v"(ahi) : "v"(word), "v"(w));
}

// ---------------- fused hist + setup (independent work, disjoint block ranges) ----------------

#define HB ((ETOT + 255) / 256)             // hist blocks
#define SN1 (FIN * HC)                      // Wt1
#define SN2 (SN1 + HC * HC)                 // Wt2
#define SN3 (SN2 + HC * CH)                 // Wtf
#define SN4 (SN3 + (2 * NN * FIN) / 4)      // x convert (vec4)
#define SB ((SN4 + 255) / 256)              // setup blocks

__global__ void k_hist_setup(const int* __restrict__ ei, int* __restrict__ counts,
                             const float* __restrict__ x, const float* __restrict__ W1,
                             const float* __restrict__ W2, const float* __restrict__ Wf,
                             ushort_t* __restrict__ Xh, ushort_t* __restrict__ Wt1,
                             ushort_t* __restrict__ Wt2, ushort_t* __restrict__ Wtf) {
    int blk = blockIdx.x;
    if (blk < HB) {
        int e = blk * 256 + threadIdx.x;
        if (e >= ETOT) return;
        int d = (e < NE) ? ei[NE + e] : (e - NE);
        atomicAdd(&counts[d], 1);
    } else {
        int i = (blk - HB) * 256 + threadIdx.x;
        if (i < SN1) {
            int n = i / FIN, k = i - n * FIN;
            Wt1[i] = f2h_bits(W1[(size_t)k * HC + n]);
        } else if (i < SN2) {
            int j = i - SN1;
            int n = j / HC, k = j - n * HC;
            Wt2[j] = f2h_bits(W2[(size_t)k * HC + n]);
        } else if (i < SN3) {
            int j = i - SN2;
            int n = j / HC, k = j - n * HC;
            Wtf[j] = f2h_bits(Wf[(size_t)k * CH + n]);
        } else if (i < SN4) {
            int j = (i - SN3) * 4;
            float4 v = *reinterpret_cast<const float4*>(&x[j]);
            ushort4 u;
            u.x = f2h_bits(v.x); u.y = f2h_bits(v.y); u.z = f2h_bits(v.z); u.w = f2h_bits(v.w);
            *reinterpret_cast<ushort4*>(&Xh[j]) = u;
        }
    }
}

// ---------------- parallel scan: per-block reduce -> top scan -> apply ----------------

__global__ void k_scan_part(const int* __restrict__ counts, int* __restrict__ bsum) {
    __shared__ int red[256];
    int t = threadIdx.x;
    int i = blockIdx.x * 256 + t;
    red[t] = (i < NN) ? counts[i] : 0;
    __syncthreads();
#pragma unroll
    for (int off = 128; off > 0; off >>= 1) {
        if (t < off) red[t] += red[t + off];
        __syncthreads();
    }
    if (t == 0) bsum[blockIdx.x] = red[0];
}

__global__ void k_scan_top(const int* __restrict__ bsum, int* __restrict__ bpre) {
    __shared__ int s[128];
    int t = threadIdx.x;
    int own = (t < SCB) ? bsum[t] : 0;
    s[t] = own;
    __syncthreads();
#pragma unroll
    for (int off = 1; off < 128; off <<= 1) {
        int v = (t >= off) ? s[t - off] : 0;
        __syncthreads();
        s[t] += v;
        __syncthreads();
    }
    if (t < SCB) bpre[t] = s[t] - own;   // exclusive block prefix
}

__global__ void k_scan_apply(const int* __restrict__ counts, const int* __restrict__ bpre,
                             int* __restrict__ rowptr, int* __restrict__ cursor) {
    __shared__ int s[256];
    int t = threadIdx.x;
    int i = blockIdx.x * 256 + t;
    int c = (i < NN) ? counts[i] : 0;
    s[t] = c;
    __syncthreads();
#pragma unroll
    for (int off = 1; off < 256; off <<= 1) {
        int v = (t >= off) ? s[t - off] : 0;
        __syncthreads();
        s[t] += v;
        __syncthreads();
    }
    int ex = s[t] - c + bpre[blockIdx.x];
    if (i < NN) { rowptr[i] = ex; cursor[i] = ex; }
    if (i == NN - 1) rowptr[NN] = ex + c;
}

__global__ void k_scatter(const int* __restrict__ ei, int* __restrict__ cursor,
                          int* __restrict__ col) {
    int e = blockIdx.x * blockDim.x + threadIdx.x;
    if (e >= ETOT) return;
    int s, d;
    if (e < NE) { s = ei[e]; d = ei[NE + e]; }
    else        { s = e - NE; d = s; }
    int pos = atomicAdd(&cursor[d], 1);
    col[pos] = s;
}

// ---------------- 128x128 f16 MFMA GEMM + fused attention scores ----------------

__global__ __launch_bounds__(256) void k_gemm128(const ushort_t* __restrict__ A,
                                                 const ushort_t* __restrict__ Bt,
                                                 ushort_t* __restrict__ Ch,
                                                 const float* __restrict__ a_src,
                                                 const float* __restrict__ a_dst,
                                                 float* __restrict__ ssrc,
                                                 float* __restrict__ sdst,
                                                 int M, int K, int NC) {
    __shared__ ushort_t As[128 * 40];   // pad: 80B stride -> 2-way (free)
    __shared__ ushort_t Bs[128 * 40];
    int tid = threadIdx.x;
    int wave = tid >> 6, lane = tid & 63;
    int wr = wave >> 1, wc = wave & 1;
    int row0 = blockIdx.x * 128, col0 = blockIdx.y * 128;

    f32x4 acc[4][4];
#pragma unroll
    for (int i = 0; i < 4; ++i)
#pragma unroll
        for (int j = 0; j < 4; ++j) acc[i][j] = (f32x4){0.f, 0.f, 0.f, 0.f};

    int srow = tid >> 2;
    int sk8 = (tid & 3) * 8;
    int l15 = lane & 15, lk = (lane >> 4) * 8;

    int ra0 = min(row0 + srow, M - 1);
    int ra1 = min(row0 + 64 + srow, M - 1);

    for (int k0 = 0; k0 < K; k0 += 32) {
        uint4 a0 = *reinterpret_cast<const uint4*>(&A[(size_t)ra0 * K + k0 + sk8]);
        uint4 a1 = *reinterpret_cast<const uint4*>(&A[(size_t)ra1 * K + k0 + sk8]);
        uint4 b0 = *reinterpret_cast<const uint4*>(&Bt[(size_t)(col0 + srow) * K + k0 + sk8]);
        uint4 b1 = *reinterpret_cast<const uint4*>(&Bt[(size_t)(col0 + 64 + srow) * K + k0 + sk8]);
        __syncthreads();
        *reinterpret_cast<uint4*>(&As[srow * 40 + sk8]) = a0;
        *reinterpret_cast<uint4*>(&As[(64 + srow) * 40 + sk8]) = a1;
        *reinterpret_cast<uint4*>(&Bs[srow * 40 + sk8]) = b0;
        *reinterpret_cast<uint4*>(&Bs[(64 + srow) * 40 + sk8]) = b1;
        __syncthreads();

        half8 af[4], bf_[4];
#pragma unroll
        for (int m = 0; m < 4; ++m)
            af[m] = *reinterpret_cast<const half8*>(&As[(wr * 64 + m * 16 + l15) * 40 + lk]);
#pragma unroll
        for (int nf = 0; nf < 4; ++nf)
            bf_[nf] = *reinterpret_cast<const half8*>(&Bs[(wc * 64 + nf * 16 + l15) * 40 + lk]);
#pragma unroll
        for (int m = 0; m < 4; ++m)
#pragma unroll
            for (int nf = 0; nf < 4; ++nf)
                acc[m][nf] = __builtin_amdgcn_mfma_f32_16x16x32_f16(af[m], bf_[nf], acc[m][nf], 0, 0, 0);
    }

    // C store (f16)
#pragma unroll
    for (int m = 0; m < 4; ++m)
#pragma unroll
        for (int nf = 0; nf < 4; ++nf) {
            int colc = col0 + wc * 64 + nf * 16 + l15;
#pragma unroll
            for (int j = 0; j < 4; ++j) {
                int row = row0 + wr * 64 + m * 16 + (lane >> 4) * 4 + j;
                if (row < M) Ch[(size_t)row * NC + colc] = f2h_bits(acc[m][nf][j]);
            }
        }

    // fused scores: this wave's 64 cols = one full head
    if (ssrc) {
        int head = (col0 >> 6) + wc;
        float as4[4], ad4[4];
#pragma unroll
        for (int nf = 0; nf < 4; ++nf) {
            as4[nf] = a_src[head * 64 + nf * 16 + l15];
            ad4[nf] = a_dst[head * 64 + nf * 16 + l15];
        }
#pragma unroll
        for (int m = 0; m < 4; ++m)
#pragma unroll
            for (int j = 0; j < 4; ++j) {
                float ps = acc[m][0][j] * as4[0] + acc[m][1][j] * as4[1]
                         + acc[m][2][j] * as4[2] + acc[m][3][j] * as4[3];
                float pd = acc[m][0][j] * ad4[0] + acc[m][1][j] * ad4[1]
                         + acc[m][2][j] * ad4[2] + acc[m][3][j] * ad4[3];
#pragma unroll
                for (int off = 1; off < 16; off <<= 1) {
                    ps += __shfl_xor(ps, off);
                    pd += __shfl_xor(pd, off);
                }
                int row = row0 + wr * 64 + m * 16 + (lane >> 4) * 4 + j;
                if (l15 == 0 && row < M) {
                    ssrc[(size_t)row * NH + head] = ps;
                    sdst[(size_t)row * NH + head] = pd;
                }
            }
    }
}

// ---------------- 64x64 f16 MFMA GEMM (final projection, f32 out + bias) ----------------

__global__ __launch_bounds__(256) void k_gemm_mfma(const ushort_t* __restrict__ A,
                                                   const ushort_t* __restrict__ Bt,
                                                   float* __restrict__ Cf,
                                                   const float* __restrict__ bias,
                                                   int M, int K, int NC) {
    __shared__ ushort_t As[64][40];
    __shared__ ushort_t Bs[64][40];
    int tid = threadIdx.x;
    int wave = tid >> 6, lane = tid & 63;
    int wr = wave >> 1, wc = wave & 1;
    int row0 = blockIdx.x * 64, col0 = blockIdx.y * 64;

    f32x4 acc[2][2];
#pragma unroll
    for (int i = 0; i < 2; ++i)
#pragma unroll
        for (int j = 0; j < 2; ++j) acc[i][j] = (f32x4){0.f, 0.f, 0.f, 0.f};

    int sr = tid >> 2;
    int sk = (tid & 3) * 8;
    int l15 = lane & 15, lk = (lane >> 4) * 8;

    for (int k0 = 0; k0 < K; k0 += 32) {
        uint4 av = make_uint4(0, 0, 0, 0);
        int rowg = row0 + sr;
        if (rowg < M) av = *reinterpret_cast<const uint4*>(&A[(size_t)rowg * K + k0 + sk]);
        uint4 bv = *reinterpret_cast<const uint4*>(&Bt[(size_t)(col0 + sr) * K + k0 + sk]);
        __syncthreads();
        *reinterpret_cast<uint4*>(&As[sr][sk]) = av;
        *reinterpret_cast<uint4*>(&Bs[sr][sk]) = bv;
        __syncthreads();

        half8 a0 = *reinterpret_cast<const half8*>(&As[wr * 32 + l15][lk]);
        half8 a1 = *reinterpret_cast<const half8*>(&As[wr * 32 + 16 + l15][lk]);
        half8 b0 = *reinterpret_cast<const half8*>(&Bs[wc * 32 + l15][lk]);
        half8 b1 = *reinterpret_cast<const half8*>(&Bs[wc * 32 + 16 + l15][lk]);
        acc[0][0] = __builtin_amdgcn_mfma_f32_16x16x32_f16(a0, b0, acc[0][0], 0, 0, 0);
        acc[0][1] = __builtin_amdgcn_mfma_f32_16x16x32_f16(a0, b1, acc[0][1], 0, 0, 0);
        acc[1][0] = __builtin_amdgcn_mfma_f32_16x16x32_f16(a1, b0, acc[1][0], 0, 0, 0);
        acc[1][1] = __builtin_amdgcn_mfma_f32_16x16x32_f16(a1, b1, acc[1][1], 0, 0, 0);
    }

#pragma unroll
    for (int fr = 0; fr < 2; ++fr)
#pragma unroll
        for (int fc = 0; fc < 2; ++fc) {
            int colc = col0 + wc * 32 + fc * 16 + l15;
#pragma unroll
            for (int j = 0; j < 4; ++j) {
                int row = row0 + wr * 32 + fr * 16 + (lane >> 4) * 4 + j;
                if (row < M) Cf[(size_t)row * NC + colc] = acc[fr][fc][j] + bias[colc];
            }
        }
}

// ---------------- edge softmax + aggregation: one wave per (node, batch) ----------------
// Round-10 form + fma_mix gather + (edge,head)-parallel phase A:
// lane = ea*4 + ha covers 16 edges x 4 heads per step — 1 exp per lane instead of
// 4 exps on ~17/64 active lanes. Denominator: shfl_xor over strides 4..32 then
// 4-float LDS broadcast. EST=80 keeps LDS conflicts <=2-way (free).

__global__ __launch_bounds__(256) void k_agg(const ushort_t* __restrict__ hb,  // [2*NN][HC] f16
                                             const float* __restrict__ ssrc,   // [2*NN][NH]
                                             const float* __restrict__ sdst,
                                             const int* __restrict__ rowptr,
                                             const int* __restrict__ col,
                                             const float* __restrict__ bias,
                                             ushort_t* __restrict__ outh,      // [2*NN][HC] f16
                                             int do_elu) {
    __shared__ int cols_lds[4][CAP];
    __shared__ float e_lds[4][4 * EST];
    __shared__ float den_lds[4][4];
    int wave = threadIdx.x >> 6, lane = threadIdx.x & 63;
    int gw = blockIdx.x * 4 + wave;      // global wave id in [0, 2*NN)
    int b = (gw >= NN) ? 1 : 0;
    int n = gw - b * NN;
    int* colw = cols_lds[wave];
    float* ew = e_lds[wave];
    int start = rowptr[n];
    int deg = rowptr[n + 1] - start;
    int es = lane >> 5;          // edge slot (phase C)
    int cg = lane & 31;          // channel group: ch [8cg, 8cg+8)
    int hd = cg >> 3;            // head of this lane's channels
    int ea = lane >> 2;          // edge index (phase A), 0..15
    int ha = lane & 3;           // head (phase A)

    const ushort_t* hbase = hb + (size_t)b * NN * HC;
    const float* ssrcb = ssrc + (size_t)b * NN * NH;

    float sdh = sdst[((size_t)b * NN + n) * NH + ha];   // this lane's head's dst score

    float pdp = 0.f;             // denominator partial (head ha, edges ea::16)
    float acc[8];
#pragma unroll
    for (int j = 0; j < 8; ++j) acc[j] = 0.f;

    const int cg8 = cg * 8;

    for (int c0 = 0; c0 < deg; c0 += CAP) {
        int cnt = min(CAP, deg - c0);
        int cnt8 = (cnt + 7) & ~7;

        // phase A: (edge,head)-parallel — 16 edges x 4 heads per step
        for (int i0 = 0; i0 < cnt8; i0 += 16) {
            int i = i0 + ea;
            if (i < cnt) {
                int s = col[start + c0 + i];
                if (ha == 0) colw[i] = s * HC;
                float e = ssrcb[(size_t)s * NH + ha] + sdh;
                e = fmaxf(e, NEG_SLOPE * e);
                float w = __expf(e);
                ew[ha * EST + i] = w;
                pdp += w;
            } else {
                if (ha == 0) colw[i] = 0;
                ew[ha * EST + i] = 0.f;
            }
        }

        // phase C: edge-parallel gather, 8 edges/iter, 4x16B loads in flight per lane,
        // fused cvt+fma via v_fma_mix_f32
        for (int i = 0; i < cnt8; i += 8) {
            int i0 = i + es, i1 = i + 2 + es, i2 = i + 4 + es, i3 = i + 6 + es;
            int o0 = colw[i0], o1 = colw[i1], o2 = colw[i2], o3 = colw[i3];
            float w0 = ew[hd * EST + i0], w1 = ew[hd * EST + i1];
            float w2 = ew[hd * EST + i2], w3 = ew[hd * EST + i3];
            uint4 u0 = *reinterpret_cast<const uint4*>(hbase + o0 + cg8);
            uint4 u1 = *reinterpret_cast<const uint4*>(hbase + o1 + cg8);
            uint4 u2 = *reinterpret_cast<const uint4*>(hbase + o2 + cg8);
            uint4 u3 = *reinterpret_cast<const uint4*>(hbase + o3 + cg8);
            fma_mix_pair(acc[0], acc[1], u0.x, w0);
            fma_mix_pair(acc[2], acc[3], u0.y, w0);
            fma_mix_pair(acc[4], acc[5], u0.z, w0);
            fma_mix_pair(acc[6], acc[7], u0.w, w0);
            fma_mix_pair(acc[0], acc[1], u1.x, w1);
            fma_mix_pair(acc[2], acc[3], u1.y, w1);
            fma_mix_pair(acc[4], acc[5], u1.z, w1);
            fma_mix_pair(acc[6], acc[7], u1.w, w1);
            fma_mix_pair(acc[0], acc[1], u2.x, w2);
            fma_mix_pair(acc[2], acc[3], u2.y, w2);
            fma_mix_pair(acc[4], acc[5], u2.z, w2);
            fma_mix_pair(acc[6], acc[7], u2.w, w2);
            fma_mix_pair(acc[0], acc[1], u3.x, w3);
            fma_mix_pair(acc[2], acc[3], u3.y, w3);
            fma_mix_pair(acc[4], acc[5], u3.z, w3);
            fma_mix_pair(acc[6], acc[7], u3.w, w3);
        }
    }

    // denominator: reduce over edge groups (strides 4..32 keep head fixed)
#pragma unroll
    for (int off = 4; off < 64; off <<= 1) pdp += __shfl_xor(pdp, off);
    if (lane < 4) den_lds[wave][ha] = pdp;   // lanes 0..3 hold heads 0..3

    // reduce acc across edge slots
#pragma unroll
    for (int j = 0; j < 8; ++j) acc[j] += __shfl_xor(acc[j], 32);

    if (es == 0) {
        float inv = 1.0f / den_lds[wave][hd];
        float4 b0 = *reinterpret_cast<const float4*>(&bias[cg8]);
        float4 b1 = *reinterpret_cast<const float4*>(&bias[cg8 + 4]);
        float bv[8] = {b0.x, b0.y, b0.z, b0.w, b1.x, b1.y, b1.z, b1.w};
        ushort_t o[8];
#pragma unroll
        for (int j = 0; j < 8; ++j) {
            float r = acc[j] * inv + bv[j];
            if (do_elu && r < 0.f) r = expm1f(r);
            o[j] = f2h_bits(r);
        }
        *reinterpret_cast<uint4*>(&outh[((size_t)b * NN + n) * HC + cg8]) =
            *reinterpret_cast<uint4*>(&o[0]);
    }
}

// ---------------- launch ----------------

extern "C" void kernel_launch(void* const* d_in, const int* in_sizes, int n_in,
                              void* d_out, int out_size, void* d_ws, size_t ws_size,
                              hipStream_t stream) {
    const float* x      = (const float*)d_in[0];   // [2, NN, FIN]
    const int*   ei     = (const int*)d_in[1];     // [2, NE]
    const float* W1     = (const float*)d_in[2];   // [FIN, HC]
    const float* a_src1 = (const float*)d_in[3];
    const float* a_dst1 = (const float*)d_in[4];
    const float* b1     = (const float*)d_in[5];
    const float* W2     = (const float*)d_in[6];   // [HC, HC]
    const float* a_src2 = (const float*)d_in[7];
    const float* a_dst2 = (const float*)d_in[8];
    const float* b2     = (const float*)d_in[9];
    const float* Wf     = (const float*)d_in[10];  // [HC, CH]
    const float* bf     = (const float*)d_in[11];
    float* out = (float*)d_out;                    // [2, NN, CH]

    const int M2 = 2 * NN;
    float* ws = (float*)d_ws;
    float* Ssrc = ws;                              // M2*NH
    float* Sdst = Ssrc + (size_t)M2 * NH;          // M2*NH
    ushort_t* Hb16 = (ushort_t*)(Sdst + (size_t)M2 * NH);  // M2*HC f16 (gemm out)
    ushort_t* Ob16 = Hb16 + (size_t)M2 * HC;       // M2*HC f16 (agg out)
    ushort_t* Xb16 = Ob16 + (size_t)M2 * HC;       // M2*FIN f16
    ushort_t* Wt1  = Xb16 + (size_t)M2 * FIN;      // HC*FIN
    ushort_t* Wt2  = Wt1 + (size_t)HC * FIN;       // HC*HC
    ushort_t* Wtf  = Wt2 + (size_t)HC * HC;        // CH*HC
    int* counts = (int*)(Wtf + (size_t)CH * HC);
    int* rowptr = counts + NN;                     // NN+1
    int* cursor = rowptr + (NN + 1);
    int* colidx = cursor + NN;                     // ETOT
    int* bsum   = colidx + ETOT;                   // SCB
    int* bpre   = bsum + SCB;                      // SCB

    // ---- CSR build (hist fused with setup; parallel scan) ----
    hipMemsetAsync(counts, 0, (size_t)NN * sizeof(int), stream);
    k_hist_setup<<<HB + SB, 256, 0, stream>>>(ei, counts, x, W1, W2, Wf,
                                              Xb16, Wt1, Wt2, Wtf);
    k_scan_part<<<SCB, 256, 0, stream>>>(counts, bsum);
    k_scan_top<<<1, 128, 0, stream>>>(bsum, bpre);
    k_scan_apply<<<SCB, 256, 0, stream>>>(counts, bpre, rowptr, cursor);
    k_scatter<<<(ETOT + 255) / 256, 256, 0, stream>>>(ei, cursor, colidx);

    const int gM128 = (M2 + 127) / 128;        // 313
    const int gAgg = M2 / 4;                   // 10000 blocks x 4 waves
    // layer 1 (scores fused into GEMM epilogue)
    k_gemm128<<<dim3(gM128, HC / 128), 256, 0, stream>>>(Xb16, Wt1, Hb16, a_src1, a_dst1,
                                                         Ssrc, Sdst, M2, FIN, HC);
    k_agg<<<gAgg, 256, 0, stream>>>(Hb16, Ssrc, Sdst, rowptr, colidx, b1, Ob16, 1);
    // layer 2
    k_gemm128<<<dim3(gM128, HC / 128), 256, 0, stream>>>(Ob16, Wt2, Hb16, a_src2, a_dst2,
                                                         Ssrc, Sdst, M2, HC, HC);
    k_agg<<<gAgg, 256, 0, stream>>>(Hb16, Ssrc, Sdst, rowptr, colidx, b2, Ob16, 0);
    // final projection (64-wide): f32 out + bias
    k_gemm_mfma<<<dim3((M2 + 63) / 64, CH / 64), 256, 0, stream>>>(Ob16, Wtf, out, bf, M2, HC, CH);
}